// Round 12
// baseline (282.136 us; speedup 1.0000x reference)
//
#include <hip/hip_runtime.h>

// RGCN: N=50000, E=600000, D=64, R=65, L=2.
// out_i = relu( sum_r mean_{j in N_r(i)} x_j@W_r + x_i@root + b ) + relu( x_i@res_W + res_b )
// Counting-sort pipeline (relation-sort -> MFMA W reuse; dst-sort -> CSR gather).
// Round-12: cnt[R][N] table eliminated. deg via direct atomics (L2-merged);
// mean-scale derived per row slot by O(deg^2) scale_k from orel[] and applied in
// gather (r11's scatter paid 26MB of XCD-duplicated random c16 fetches).
// Keeps r9-r11 fixes: parallel scans, SORT_BS=2048, fused launches, bf16 io.

constexpr int NN  = 50000;
constexpr int EE  = 600000;
constexpr int DIM = 64;
constexpr int RR  = 65;
constexpr int CHUNK = 256;                        // edges per msgm relation-chunk
constexpr int MAXCHUNKS = EE / CHUNK + RR + 8;
constexpr int SORT_BS = 2048;                     // edges per sort block
constexpr int NSB = (EE + SORT_BS - 1) / SORT_BS; // 293
constexpr int SCAN_BS = 1024;
constexpr int SCAN_NB = (NN + SCAN_BS - 1) / SCAN_BS; // 49
constexpr int XNB = 64;                           // nodes per xform block

typedef __attribute__((ext_vector_type(8))) short short8v;
typedef __attribute__((ext_vector_type(4))) float floatx4;

__device__ inline unsigned short f2bf(float f) {
  unsigned int u = __float_as_uint(f);
  return (unsigned short)((u + 0x7fffu + ((u >> 16) & 1u)) >> 16);  // RNE
}
__device__ inline float bf2f(unsigned short v) {
  return __uint_as_float(((unsigned int)v) << 16);
}

// ---------------- fused setup kernel: zero deg | cvt W | cvt x ----------------

constexpr int ZN4 = (NN + 3) / 4;                 // int4 count of deg (200KB)
constexpr int ZB  = (ZN4 + 255) / 256;            // 49
constexpr int CW4 = 2 * RR * DIM * DIM / 4;       // float4 count of W
constexpr int CB  = (CW4 + 255) / 256;
constexpr int HB  = (NN * DIM / 8 + 255) / 256;

__global__ __launch_bounds__(256) void setup_k(int4* __restrict__ zp,
                                               const float* __restrict__ W,
                                               unsigned short* __restrict__ WT,
                                               const float* __restrict__ x,
                                               unsigned short* __restrict__ hbf) {
  const int b = blockIdx.x;
  if (b < ZB) {
    const int i = b * 256 + threadIdx.x;
    if (i < ZN4) zp[i] = make_int4(0, 0, 0, 0);
  } else if (b < ZB + CB) {
    // W[l][r][k][c] f32 -> WT[l*R+r][c][k] bf16 (transposed)
    const int tid = (b - ZB) * 256 + threadIdx.x;
    if (tid >= CW4) return;
    const int base = tid * 4;
    const int mat = base >> 12, rem = base & 4095;
    const int k = rem >> 6, c0 = rem & 63;
    const float4 v = *reinterpret_cast<const float4*>(W + base);
    unsigned short* o = WT + (size_t)mat * 4096;
    o[(c0 + 0) * 64 + k] = f2bf(v.x);
    o[(c0 + 1) * 64 + k] = f2bf(v.y);
    o[(c0 + 2) * 64 + k] = f2bf(v.z);
    o[(c0 + 3) * 64 + k] = f2bf(v.w);
  } else {
    const int tid = (b - ZB - CB) * 256 + threadIdx.x;   // 8 elems per thread
    if (tid * 8 >= NN * DIM) return;
    const float4 v0 = reinterpret_cast<const float4*>(x)[tid * 2];
    const float4 v1 = reinterpret_cast<const float4*>(x)[tid * 2 + 1];
    ushort4 a, c;
    a.x = f2bf(v0.x); a.y = f2bf(v0.y); a.z = f2bf(v0.z); a.w = f2bf(v0.w);
    c.x = f2bf(v1.x); c.y = f2bf(v1.y); c.z = f2bf(v1.z); c.w = f2bf(v1.w);
    reinterpret_cast<ushort4*>(hbf)[tid * 2] = a;
    reinterpret_cast<ushort4*>(hbf)[tid * 2 + 1] = c;
  }
}

// Fused: deg direct atomics (50k addrs, L2-merged) + per-block LDS type hist.
__global__ __launch_bounds__(512) void hist_k(const int* __restrict__ dst,
                                              const int* __restrict__ et,
                                              int* __restrict__ deg,
                                              int* __restrict__ bhist, int E) {
  __shared__ int lh[RR];
  if (threadIdx.x < RR) lh[threadIdx.x] = 0;
  __syncthreads();
  const int base = blockIdx.x * SORT_BS;
#pragma unroll
  for (int it = 0; it < SORT_BS / 512; ++it) {
    const int e = base + it * 512 + threadIdx.x;
    if (e < E) {
      atomicAdd(&deg[dst[e]], 1);     // ~12 avg same-address contention
      atomicAdd(&lh[et[e]], 1);       // LDS
    }
  }
  __syncthreads();
  if (threadIdx.x < RR) bhist[blockIdx.x * RR + threadIdx.x] = lh[threadIdx.x];
}

// ---- fused scanA: [deg block-reduce | per-relation block prefix] ----

__global__ __launch_bounds__(1024) void scanA_k(const int* __restrict__ deg,
                                                int* __restrict__ bsum,
                                                const int* __restrict__ bhist,
                                                int* __restrict__ boffrel,
                                                int* __restrict__ total) {
  __shared__ int s[SCAN_BS];
  const int t = threadIdx.x;
  if (blockIdx.x < SCAN_NB) {
    const int idx = blockIdx.x * SCAN_BS + t;
    s[t] = (idx < NN) ? deg[idx] : 0;
    __syncthreads();
    for (int off = SCAN_BS / 2; off > 0; off >>= 1) {
      if (t < off) s[t] += s[t + off];
      __syncthreads();
    }
    if (t == 0) bsum[blockIdx.x] = s[0];
  } else {
    const int r = blockIdx.x - SCAN_NB;        // relation
    const int v = (t < NSB) ? bhist[t * RR + r] : 0;
    s[t] = v;
    __syncthreads();
    for (int off = 1; off < SCAN_BS; off <<= 1) {
      const int u = (t >= off) ? s[t - off] : 0;
      __syncthreads();
      s[t] += u;
      __syncthreads();
    }
    if (t < NSB) boffrel[t * RR + r] = s[t] - v;   // exclusive within relation
    if (t == SCAN_BS - 1) total[r] = s[SCAN_BS - 1];
  }
}

// ---- fused scanB: [wave-scan bsum | type totals -> tptr + chunks] ----

__global__ __launch_bounds__(128) void scanB_k(int* __restrict__ bsum,
                                               const int* __restrict__ total,
                                               int* __restrict__ tptrg,
                                               int4* __restrict__ chunkArr,
                                               int* __restrict__ nchunks) {
  const int t = threadIdx.x;
  if (blockIdx.x == 0) {
    if (t < 64) {
      int v = (t < SCAN_NB) ? bsum[t] : 0;
      const int orig = v;
      for (int off = 1; off < 64; off <<= 1) {
        const int u = __shfl_up(v, off, 64);
        if (t >= off) v += u;
      }
      if (t < SCAN_NB) bsum[t] = v - orig;   // exclusive
    }
  } else {
    __shared__ int tptr[RR + 1], chbase[RR + 1];
    if (t == 0) {
      int run = 0, crun = 0;
      for (int r = 0; r < RR; ++r) {
        tptr[r] = run;    run  += total[r];
        chbase[r] = crun; crun += (total[r] + CHUNK - 1) / CHUNK;
      }
      tptr[RR] = run; chbase[RR] = crun;
      *nchunks = crun;
    }
    __syncthreads();
    if (t < RR) {
      tptrg[t] = tptr[t];
      const int tot = total[t];
      const int nc = (tot + CHUNK - 1) / CHUNK;
      for (int i = 0; i < nc; ++i) {
        const int beg = tptr[t] + i * CHUNK;
        chunkArr[chbase[t] + i] = make_int4(beg, min(beg + CHUNK, tptr[t] + tot), t, 0);
      }
    }
  }
}

__global__ __launch_bounds__(1024) void scan3_k(const int* __restrict__ deg,
                                                const int* __restrict__ bsum,
                                                int* __restrict__ rowptr,
                                                int* __restrict__ poscur) {
  __shared__ int s[SCAN_BS];
  const int t = threadIdx.x;
  const int idx = blockIdx.x * SCAN_BS + t;
  const int v = (idx < NN) ? deg[idx] : 0;
  s[t] = v;
  __syncthreads();
  for (int off = 1; off < SCAN_BS; off <<= 1) {  // Hillis-Steele inclusive
    const int u = (t >= off) ? s[t - off] : 0;
    __syncthreads();
    s[t] += u;
    __syncthreads();
  }
  const int excl = bsum[blockIdx.x] + s[t] - v;
  if (idx < NN) { rowptr[idx] = excl; poscur[idx] = excl; }
  if (idx == NN - 1) rowptr[NN] = EE;
}

// Type-sorted slot q (LDS counter) + dst-sorted slot p (global atomic).
// Writes osrc/opos by q, relation by p. No cnt lookups anywhere.
__global__ __launch_bounds__(512) void scatter_k(const int* __restrict__ src,
                                                 const int* __restrict__ dst,
                                                 const int* __restrict__ et,
                                                 const int* __restrict__ boffrel,
                                                 const int* __restrict__ tptrg,
                                                 int* __restrict__ poscur,
                                                 int* __restrict__ osrc,
                                                 int* __restrict__ opos,
                                                 int* __restrict__ orel, int E) {
  __shared__ int cur[RR];
  if (threadIdx.x < RR)
    cur[threadIdx.x] = tptrg[threadIdx.x] + boffrel[blockIdx.x * RR + threadIdx.x];
  __syncthreads();
  const int base = blockIdx.x * SORT_BS;
#pragma unroll
  for (int it = 0; it < SORT_BS / 512; ++it) {
    const int e = base + it * 512 + threadIdx.x;
    if (e < E) {
      const int s = src[e], d = dst[e], r = et[e];
      const int q = atomicAdd(&cur[r], 1);       // LDS atomic, block-local
      const int p = atomicAdd(&poscur[d], 1);    // global, ~12 avg contention
      osrc[q] = s;
      opos[q] = p;
      orel[p] = r;                               // L2 write-back, 2.4MB
    }
  }
}

// Per-node O(deg^2): sc[p] = 1 / #{p2 in row : orel[p2]==orel[p]}  (== 1/cnt[d,r]).
__global__ __launch_bounds__(256) void scale_k(const int* __restrict__ rowptr,
                                               const int* __restrict__ orel,
                                               float* __restrict__ sc, int N) {
  const int n = blockIdx.x * 256 + threadIdx.x;
  if (n >= N) return;
  const int jb = rowptr[n], je = rowptr[n + 1];
  for (int j1 = jb; j1 < je; ++j1) {
    const int r1 = orel[j1];
    int c = 0;
    for (int j2 = jb; j2 < je; ++j2) c += (orel[j2] == r1) ? 1 : 0;
    sc[j1] = 1.0f / (float)c;
  }
}

// ---------------- per-layer kernels ----------------

// MFMA message kernel: one block per 256-edge relation-chunk, 4 waves x 64 edges.
// Writes RAW (unscaled) bf16 messages; scale applied in gather.
__global__ __launch_bounds__(256) void msgm_k(const unsigned short* __restrict__ hbf,
                                              const int* __restrict__ osrc,
                                              const int* __restrict__ opos,
                                              const unsigned short* __restrict__ WT,
                                              const int4* __restrict__ chunkArr,
                                              const int* __restrict__ nchunks,
                                              unsigned short* __restrict__ m) {
  const int ci = blockIdx.x;
  if (ci >= *nchunks) return;
  const int4 c = chunkArr[ci];
  const int beg = c.x, end = c.y, rel = c.z;

  __shared__ unsigned short Wl[DIM][72];   // +8 pad
  {
    const float4* s4 = reinterpret_cast<const float4*>(WT + (size_t)rel * 4096);
#pragma unroll
    for (int it = 0; it < 2; ++it) {
      const int seg = threadIdx.x + it * 256;   // 512 x 16B segments
      const int row = seg >> 3, s8 = seg & 7;
      *reinterpret_cast<float4*>(&Wl[row][s8 * 8]) = s4[seg];
    }
  }
  __syncthreads();

  const int w  = threadIdx.x >> 6;
  const int l  = threadIdx.x & 63;
  const int lr = l & 15, lq = l >> 4;

  const int ebase = beg + w * 64;
  if (ebase >= end) return;                // no barriers after this point

  short8v a[4][2];
#pragma unroll
  for (int ct = 0; ct < 4; ++ct)
#pragma unroll
    for (int kk = 0; kk < 2; ++kk)
      a[ct][kk] = *reinterpret_cast<const short8v*>(&Wl[ct * 16 + lr][kk * 32 + lq * 8]);

  short8v b[4][2];
  int eidx[4];
#pragma unroll
  for (int et = 0; et < 4; ++et) {
    eidx[et] = ebase + et * 16 + lr;
    const int e = min(eidx[et], end - 1);  // clamp (safe dup, store guarded)
    const int s = osrc[e];
    const unsigned short* hp = hbf + (size_t)s * DIM;
    b[et][0] = *reinterpret_cast<const short8v*>(hp + lq * 8);
    b[et][1] = *reinterpret_cast<const short8v*>(hp + 32 + lq * 8);
  }

  floatx4 acc[4][4];
#pragma unroll
  for (int ct = 0; ct < 4; ++ct)
#pragma unroll
    for (int et = 0; et < 4; ++et)
      acc[ct][et] = (floatx4){0.f, 0.f, 0.f, 0.f};

#pragma unroll
  for (int kk = 0; kk < 2; ++kk)
#pragma unroll
    for (int ct = 0; ct < 4; ++ct)
#pragma unroll
      for (int et = 0; et < 4; ++et)
        acc[ct][et] = __builtin_amdgcn_mfma_f32_16x16x32_bf16(a[ct][kk], b[et][kk],
                                                              acc[ct][et], 0, 0, 0);

#pragma unroll
  for (int et = 0; et < 4; ++et) {
    const int e = eidx[et];
    if (e < end) {
      unsigned short* op = m + (size_t)opos[e] * DIM;
#pragma unroll
      for (int ct = 0; ct < 4; ++ct) {
        ushort4 o;
        o.x = f2bf(acc[ct][et][0]);
        o.y = f2bf(acc[ct][et][1]);
        o.z = f2bf(acc[ct][et][2]);
        o.w = f2bf(acc[ct][et][3]);
        *reinterpret_cast<ushort4*>(op + ct * 16 + lq * 4) = o;
      }
    }
  }
}

// Dense node transform: rt16 = bf16(h@root + b), rs16 = bf16(relu(h@rw + rb)).
template<bool F32SRC>
__global__ __launch_bounds__(256) void xform_k(const void* __restrict__ hsrc,
                                               const float* __restrict__ root,
                                               const float* __restrict__ bias,
                                               const float* __restrict__ rw,
                                               const float* __restrict__ rb,
                                               unsigned short* __restrict__ rt16,
                                               unsigned short* __restrict__ rs16, int N) {
  __shared__ float Wl0[DIM * DIM];
  __shared__ float Wl1[DIM * DIM];
  __shared__ float xs[XNB][68];
#pragma unroll
  for (int i = 0; i < 4; ++i) {
    reinterpret_cast<float4*>(Wl0)[threadIdx.x + i * 256] =
        reinterpret_cast<const float4*>(root)[threadIdx.x + i * 256];
    reinterpret_cast<float4*>(Wl1)[threadIdx.x + i * 256] =
        reinterpret_cast<const float4*>(rw)[threadIdx.x + i * 256];
  }

  const int g = threadIdx.x >> 4, li = threadIdx.x & 15;
  const int base = blockIdx.x * XNB;
#pragma unroll
  for (int r = 0; r < 4; ++r) {
    const int n = base + g * 4 + r;
    float4 v = make_float4(0.f, 0.f, 0.f, 0.f);
    if (n < N) {
      if (F32SRC) {
        v = *reinterpret_cast<const float4*>((const float*)hsrc + (size_t)n * DIM + li * 4);
      } else {
        const ushort4 u = *reinterpret_cast<const ushort4*>(
            (const unsigned short*)hsrc + (size_t)n * DIM + li * 4);
        v = make_float4(bf2f(u.x), bf2f(u.y), bf2f(u.z), bf2f(u.w));
      }
    }
    *reinterpret_cast<float4*>(&xs[g * 4 + r][li * 4]) = v;
  }
  __syncthreads();

  float aR[4][4], aS[4][4];
#pragma unroll
  for (int r = 0; r < 4; ++r)
#pragma unroll
    for (int q = 0; q < 4; ++q) { aR[r][q] = 0.f; aS[r][q] = 0.f; }

#pragma unroll 4
  for (int k = 0; k < DIM; ++k) {
    const float4 wr = *reinterpret_cast<const float4*>(&Wl0[k * DIM + li * 4]);
    const float4 wv = *reinterpret_cast<const float4*>(&Wl1[k * DIM + li * 4]);
#pragma unroll
    for (int r = 0; r < 4; ++r) {
      const float xv = xs[g * 4 + r][k];
      aR[r][0] += xv * wr.x; aR[r][1] += xv * wr.y; aR[r][2] += xv * wr.z; aR[r][3] += xv * wr.w;
      aS[r][0] += xv * wv.x; aS[r][1] += xv * wv.y; aS[r][2] += xv * wv.z; aS[r][3] += xv * wv.w;
    }
  }

  const float4 bv = reinterpret_cast<const float4*>(bias)[li];
  const float4 cv = reinterpret_cast<const float4*>(rb)[li];
#pragma unroll
  for (int r = 0; r < 4; ++r) {
    const int n = base + g * 4 + r;
    if (n < N) {
      ushort4 t, s;
      t.x = f2bf(aR[r][0] + bv.x); t.y = f2bf(aR[r][1] + bv.y);
      t.z = f2bf(aR[r][2] + bv.z); t.w = f2bf(aR[r][3] + bv.w);
      s.x = f2bf(fmaxf(aS[r][0] + cv.x, 0.f)); s.y = f2bf(fmaxf(aS[r][1] + cv.y, 0.f));
      s.z = f2bf(fmaxf(aS[r][2] + cv.z, 0.f)); s.w = f2bf(fmaxf(aS[r][3] + cv.w, 0.f));
      *reinterpret_cast<ushort4*>(rt16 + (size_t)n * DIM + li * 4) = t;
      *reinterpret_cast<ushort4*>(rs16 + (size_t)n * DIM + li * 4) = s;
    }
  }
}

// Streaming epilogue: out = relu(sum_j sc[j]*msg[j] + rt) + rs.
template<bool OUT_BF16>
__global__ __launch_bounds__(256) void gather3_k(const unsigned short* __restrict__ m,
                                                 const float* __restrict__ sc,
                                                 const int* __restrict__ rowptr,
                                                 const unsigned short* __restrict__ rt16,
                                                 const unsigned short* __restrict__ rs16,
                                                 void* __restrict__ hout, int N) {
  const int g = threadIdx.x >> 4, li = threadIdx.x & 15;
  const int n = blockIdx.x * 16 + g;
  if (n >= N) return;

  float a0 = 0.f, a1 = 0.f, a2 = 0.f, a3 = 0.f;
  const int jb = rowptr[n], je = rowptr[n + 1];
  int j = jb;
  for (; j + 8 <= je; j += 8) {            // 8 independent loads in flight
    ushort4 v[8];
    float cc[8];
#pragma unroll
    for (int u = 0; u < 8; ++u) {
      v[u] = *reinterpret_cast<const ushort4*>(m + (size_t)(j + u) * DIM + li * 4);
      cc[u] = sc[j + u];
    }
#pragma unroll
    for (int u = 0; u < 8; ++u) {
      a0 += cc[u] * bf2f(v[u].x); a1 += cc[u] * bf2f(v[u].y);
      a2 += cc[u] * bf2f(v[u].z); a3 += cc[u] * bf2f(v[u].w);
    }
  }
  for (; j + 4 <= je; j += 4) {
    ushort4 v[4];
    float cc[4];
#pragma unroll
    for (int u = 0; u < 4; ++u) {
      v[u] = *reinterpret_cast<const ushort4*>(m + (size_t)(j + u) * DIM + li * 4);
      cc[u] = sc[j + u];
    }
#pragma unroll
    for (int u = 0; u < 4; ++u) {
      a0 += cc[u] * bf2f(v[u].x); a1 += cc[u] * bf2f(v[u].y);
      a2 += cc[u] * bf2f(v[u].z); a3 += cc[u] * bf2f(v[u].w);
    }
  }
  for (; j < je; ++j) {
    const float cc = sc[j];
    const ushort4 v = *reinterpret_cast<const ushort4*>(m + (size_t)j * DIM + li * 4);
    a0 += cc * bf2f(v.x); a1 += cc * bf2f(v.y); a2 += cc * bf2f(v.z); a3 += cc * bf2f(v.w);
  }

  const ushort4 tu = *reinterpret_cast<const ushort4*>(rt16 + (size_t)n * DIM + li * 4);
  const ushort4 su = *reinterpret_cast<const ushort4*>(rs16 + (size_t)n * DIM + li * 4);
  const float o0 = fmaxf(a0 + bf2f(tu.x), 0.f) + bf2f(su.x);
  const float o1 = fmaxf(a1 + bf2f(tu.y), 0.f) + bf2f(su.y);
  const float o2 = fmaxf(a2 + bf2f(tu.z), 0.f) + bf2f(su.z);
  const float o3 = fmaxf(a3 + bf2f(tu.w), 0.f) + bf2f(su.w);
  if (OUT_BF16) {
    ushort4 o;
    o.x = f2bf(o0); o.y = f2bf(o1); o.z = f2bf(o2); o.w = f2bf(o3);
    *reinterpret_cast<ushort4*>((unsigned short*)hout + (size_t)n * DIM + li * 4) = o;
  } else {
    *reinterpret_cast<float4*>((float*)hout + (size_t)n * DIM + li * 4) =
        make_float4(o0, o1, o2, o3);
  }
}

// ---------------- last-resort fallback (float atomics, self-contained) ----------------

__global__ __launch_bounds__(256) void count_k(const int* __restrict__ dst,
                                               const int* __restrict__ et,
                                               int* __restrict__ cnt, int E) {
  int e = blockIdx.x * 256 + threadIdx.x;
  if (e < E) atomicAdd(&cnt[dst[e] * RR + et[e]], 1);
}

__global__ __launch_bounds__(256) void edge_k(const float* __restrict__ h,
                                              const int* __restrict__ src,
                                              const int* __restrict__ dst,
                                              const int* __restrict__ et,
                                              const float* __restrict__ W,
                                              const int* __restrict__ cnt,
                                              float* __restrict__ accum, int E) {
  __shared__ float xs[16][68];
  const int g = threadIdx.x >> 4, li = threadIdx.x & 15;
  const int e = blockIdx.x * 16 + g;
  if (e >= E) return;
  const int s = src[e], d = dst[e], t = et[e];
  *reinterpret_cast<float4*>(&xs[g][li * 4]) =
      *reinterpret_cast<const float4*>(h + (size_t)s * DIM + li * 4);
  const float* Wt = W + (size_t)t * (DIM * DIM) + li * 4;
  float a0 = 0.f, a1 = 0.f, a2 = 0.f, a3 = 0.f;
#pragma unroll 8
  for (int k = 0; k < DIM; ++k) {
    const float xd = xs[g][k];
    const float4 w = *reinterpret_cast<const float4*>(Wt + k * DIM);
    a0 += xd * w.x; a1 += xd * w.y; a2 += xd * w.z; a3 += xd * w.w;
  }
  const float sc = 1.0f / (float)cnt[d * RR + t];
  float* o = accum + (size_t)d * DIM + li * 4;
  unsafeAtomicAdd(o + 0, a0 * sc);
  unsafeAtomicAdd(o + 1, a1 * sc);
  unsafeAtomicAdd(o + 2, a2 * sc);
  unsafeAtomicAdd(o + 3, a3 * sc);
}

__global__ __launch_bounds__(256) void node_k(const float* __restrict__ h,
                                              const float* __restrict__ root,
                                              const float* __restrict__ bias,
                                              const float* __restrict__ rw,
                                              const float* __restrict__ rb,
                                              float* __restrict__ io, int N) {
  __shared__ float xs[16][68];
  const int g = threadIdx.x >> 4, li = threadIdx.x & 15;
  const int n = blockIdx.x * 16 + g;
  if (n >= N) return;
  *reinterpret_cast<float4*>(&xs[g][li * 4]) =
      *reinterpret_cast<const float4*>(h + (size_t)n * DIM + li * 4);
  float r0 = 0.f, r1 = 0.f, r2 = 0.f, r3 = 0.f;
  float s0 = 0.f, s1 = 0.f, s2 = 0.f, s3 = 0.f;
#pragma unroll 8
  for (int k = 0; k < DIM; ++k) {
    const float hd = xs[g][k];
    const float4 w = *reinterpret_cast<const float4*>(root + k * DIM + li * 4);
    const float4 v = *reinterpret_cast<const float4*>(rw + k * DIM + li * 4);
    r0 += hd * w.x; r1 += hd * w.y; r2 += hd * w.z; r3 += hd * w.w;
    s0 += hd * v.x; s1 += hd * v.y; s2 += hd * v.z; s3 += hd * v.w;
  }
  float* o = io + (size_t)n * DIM + li * 4;
  const float4 acc = *reinterpret_cast<const float4*>(o);
  const float4 b = *reinterpret_cast<const float4*>(bias + li * 4);
  const float4 c = *reinterpret_cast<const float4*>(rb + li * 4);
  float o0 = fmaxf(acc.x + r0 + b.x, 0.f) + fmaxf(s0 + c.x, 0.f);
  float o1 = fmaxf(acc.y + r1 + b.y, 0.f) + fmaxf(s1 + c.y, 0.f);
  float o2 = fmaxf(acc.z + r2 + b.z, 0.f) + fmaxf(s2 + c.z, 0.f);
  float o3 = fmaxf(acc.w + r3 + b.w, 0.f) + fmaxf(s3 + c.w, 0.f);
  *reinterpret_cast<float4*>(o) = make_float4(o0, o1, o2, o3);
}

// ---------------- host ----------------

extern "C" void kernel_launch(void* const* d_in, const int* in_sizes, int n_in,
                              void* d_out, int out_size, void* d_ws, size_t ws_size,
                              hipStream_t stream) {
  const float* x    = (const float*)d_in[0];
  const int*   ei   = (const int*)d_in[1];
  const int*   et   = (const int*)d_in[2];
  const float* W    = (const float*)d_in[3];
  const float* root = (const float*)d_in[4];
  const float* bias = (const float*)d_in[5];
  const float* resW = (const float*)d_in[6];
  const float* resb = (const float*)d_in[7];
  float* out = (float*)d_out;

  const int* src = ei;
  const int* dstp = ei + EE;

  char* ws = (char*)d_ws;
  size_t off = 0;
  auto take = [&](size_t bytes) -> void* {
    void* p = ws + off;
    off = (off + bytes + 255) & ~(size_t)255;
    return p;
  };
  unsigned short* m = (unsigned short*)take((size_t)EE * DIM * sizeof(unsigned short));
  int* deg       = (int*)take((size_t)((NN + 3) & ~3) * sizeof(int));
  int* rowptr    = (int*)take((size_t)(NN + 1) * sizeof(int));
  int* poscur    = (int*)take((size_t)NN * sizeof(int));
  int* bhist     = (int*)take((size_t)NSB * RR * sizeof(int));
  int* boffrel   = (int*)take((size_t)NSB * RR * sizeof(int));
  int* total     = (int*)take((size_t)RR * sizeof(int));
  int* tptrg     = (int*)take((size_t)RR * sizeof(int));
  int* bsum      = (int*)take((size_t)SCAN_NB * sizeof(int));
  int* osrc      = (int*)take((size_t)EE * sizeof(int));
  int* opos      = (int*)take((size_t)EE * sizeof(int));
  int* orel      = (int*)take((size_t)EE * sizeof(int));
  float* sc      = (float*)take((size_t)EE * sizeof(float));
  int4* chunkArr = (int4*)take((size_t)MAXCHUNKS * sizeof(int4));
  int* nchunks   = (int*)take(256);
  unsigned short* rt16 = (unsigned short*)take((size_t)NN * DIM * sizeof(unsigned short));
  unsigned short* rs16 = (unsigned short*)take((size_t)NN * DIM * sizeof(unsigned short));
  unsigned short* hbf  = (unsigned short*)take((size_t)NN * DIM * sizeof(unsigned short));
  unsigned short* wbt  = (unsigned short*)take((size_t)2 * RR * DIM * DIM * sizeof(unsigned short));
  const size_t main_off = off;

  if (main_off <= ws_size) {
    // 1: fused setup (zero deg | W->bf16^T | x->bf16)
    setup_k<<<ZB + CB + HB, 256, 0, stream>>>((int4*)deg, W, wbt, x, hbf);
    // 2: histograms (deg atomics + per-block type hist)
    hist_k<<<NSB, 512, 0, stream>>>(dstp, et, deg, bhist, EE);
    // 3: [deg reduce | per-relation prefix]
    scanA_k<<<SCAN_NB + RR, 1024, 0, stream>>>(deg, bsum, bhist, boffrel, total);
    // 4: [bsum scan | type totals -> chunks]
    scanB_k<<<2, 128, 0, stream>>>(bsum, total, tptrg, chunkArr, nchunks);
    // 5: node rowptr
    scan3_k<<<SCAN_NB, 1024, 0, stream>>>(deg, bsum, rowptr, poscur);
    // 6: edge scatter (no cnt lookups)
    scatter_k<<<NSB, 512, 0, stream>>>(src, dstp, et, boffrel, tptrg, poscur,
                                       osrc, opos, orel, EE);
    // 7: per-slot mean scale from orel
    scale_k<<<(NN + 255) / 256, 256, 0, stream>>>(rowptr, orel, sc, NN);

    const int XG = (NN + XNB - 1) / XNB;
    // layer 0: x -> hbf(h1)
    xform_k<true><<<XG, 256, 0, stream>>>(x, root, bias, resW, resb, rt16, rs16, NN);
    msgm_k<<<MAXCHUNKS, 256, 0, stream>>>(hbf, osrc, opos, wbt, chunkArr, nchunks, m);
    gather3_k<true><<<(NN + 15) / 16, 256, 0, stream>>>(m, sc, rowptr, rt16, rs16, hbf, NN);
    // layer 1: hbf(h1) -> out (f32)
    xform_k<false><<<XG, 256, 0, stream>>>(hbf, root + DIM * DIM, bias + DIM,
                                           resW + DIM * DIM, resb + DIM, rt16, rs16, NN);
    msgm_k<<<MAXCHUNKS, 256, 0, stream>>>(hbf, osrc, opos,
                                          wbt + (size_t)RR * DIM * DIM, chunkArr, nchunks, m);
    gather3_k<false><<<(NN + 15) / 16, 256, 0, stream>>>(m, sc, rowptr, rt16, rs16, out, NN);
  } else {
    // ---- fallback: atomic path (needs only 25.8 MB) ----
    int* fcnt = (int*)ws;
    float* fh1 = (float*)(ws + (size_t)NN * RR * sizeof(int));
    hipMemsetAsync(fcnt, 0, (size_t)NN * RR * sizeof(int), stream);
    hipMemsetAsync(fh1, 0, (size_t)NN * DIM * sizeof(float), stream);
    hipMemsetAsync(out, 0, (size_t)NN * DIM * sizeof(float), stream);
    count_k<<<(EE + 255) / 256, 256, 0, stream>>>(dstp, et, fcnt, EE);
    edge_k<<<(EE + 15) / 16, 256, 0, stream>>>(x, src, dstp, et, W, fcnt, fh1, EE);
    node_k<<<(NN + 15) / 16, 256, 0, stream>>>(x, root, bias, resW, resb, fh1, NN);
    edge_k<<<(EE + 15) / 16, 256, 0, stream>>>(fh1, src, dstp, et,
                                               W + (size_t)RR * DIM * DIM, fcnt, out, EE);
    node_k<<<(NN + 15) / 16, 256, 0, stream>>>(fh1, root + DIM * DIM, bias + DIM,
                                               resW + DIM * DIM, resb + DIM, out, NN);
  }
}

// Round 13
// 225.644 us; speedup vs baseline: 1.2504x; 1.2504x over previous
//
#include <hip/hip_runtime.h>

// RGCN: N=50000, E=600000, D=64, R=65, L=2.
// out_i = relu( sum_r mean_{j in N_r(i)} x_j@W_r + x_i@root + b ) + relu( x_i@res_W + res_b )
// Counting-sort pipeline (relation-sort -> MFMA W reuse; dst-sort -> CSR gather).
// Round-13: r11 structure (best, 230us) with SORT_BS 2048->1024: hist/scatter are
// random-access latency-bound; 586 blocks doubles outstanding misses. r12's
// cnt-table elimination reverted (scale_k was 49us latency-bound; orel writes
// cost more than c16 reads).

constexpr int NN  = 50000;
constexpr int EE  = 600000;
constexpr int DIM = 64;
constexpr int RR  = 65;
constexpr int CHUNK = 256;                        // edges per msgm relation-chunk
constexpr int MAXCHUNKS = EE / CHUNK + RR + 8;
constexpr int SORT_BS = 1024;                     // edges per sort block
constexpr int NSB = (EE + SORT_BS - 1) / SORT_BS; // 586
constexpr int SCAN_BS = 1024;
constexpr int SCAN_NB = (NN + SCAN_BS - 1) / SCAN_BS; // 49
constexpr int XNB = 64;                           // nodes per xform block

typedef __attribute__((ext_vector_type(8))) short short8v;
typedef __attribute__((ext_vector_type(4))) float floatx4;

__device__ inline unsigned short f2bf(float f) {
  unsigned int u = __float_as_uint(f);
  return (unsigned short)((u + 0x7fffu + ((u >> 16) & 1u)) >> 16);  // RNE
}
__device__ inline float bf2f(unsigned short v) {
  return __uint_as_float(((unsigned int)v) << 16);
}

// ---------------- fused setup kernel: zero cnt | cvt W | cvt x ----------------

constexpr int ZN4 = NN * RR * 2 / 16;             // int4 count of uint16 cnt (6.5MB)
constexpr int ZB  = (ZN4 + 255) / 256;
constexpr int CW4 = 2 * RR * DIM * DIM / 4;       // float4 count of W
constexpr int CB  = (CW4 + 255) / 256;
constexpr int HB  = (NN * DIM / 8 + 255) / 256;

__global__ __launch_bounds__(256) void setup_k(int4* __restrict__ zp,
                                               const float* __restrict__ W,
                                               unsigned short* __restrict__ WT,
                                               const float* __restrict__ x,
                                               unsigned short* __restrict__ hbf) {
  const int b = blockIdx.x;
  if (b < ZB) {
    const int i = b * 256 + threadIdx.x;
    if (i < ZN4) zp[i] = make_int4(0, 0, 0, 0);
  } else if (b < ZB + CB) {
    // W[l][r][k][c] f32 -> WT[l*R+r][c][k] bf16 (transposed)
    const int tid = (b - ZB) * 256 + threadIdx.x;
    if (tid >= CW4) return;
    const int base = tid * 4;
    const int mat = base >> 12, rem = base & 4095;
    const int k = rem >> 6, c0 = rem & 63;
    const float4 v = *reinterpret_cast<const float4*>(W + base);
    unsigned short* o = WT + (size_t)mat * 4096;
    o[(c0 + 0) * 64 + k] = f2bf(v.x);
    o[(c0 + 1) * 64 + k] = f2bf(v.y);
    o[(c0 + 2) * 64 + k] = f2bf(v.z);
    o[(c0 + 3) * 64 + k] = f2bf(v.w);
  } else {
    const int tid = (b - ZB - CB) * 256 + threadIdx.x;   // 8 elems per thread
    if (tid * 8 >= NN * DIM) return;
    const float4 v0 = reinterpret_cast<const float4*>(x)[tid * 2];
    const float4 v1 = reinterpret_cast<const float4*>(x)[tid * 2 + 1];
    ushort4 a, c;
    a.x = f2bf(v0.x); a.y = f2bf(v0.y); a.z = f2bf(v0.z); a.w = f2bf(v0.w);
    c.x = f2bf(v1.x); c.y = f2bf(v1.y); c.z = f2bf(v1.z); c.w = f2bf(v1.w);
    reinterpret_cast<ushort4*>(hbf)[tid * 2] = a;
    reinterpret_cast<ushort4*>(hbf)[tid * 2 + 1] = c;
  }
}

// Fused: uint16 (d,r)-histogram via packed 32-bit atomics + per-block LDS type hist.
__global__ __launch_bounds__(512) void hist_k(const int* __restrict__ dst,
                                              const int* __restrict__ et,
                                              unsigned int* __restrict__ cnt32,
                                              int* __restrict__ bhist, int E) {
  __shared__ int lh[RR];
  if (threadIdx.x < RR) lh[threadIdx.x] = 0;
  __syncthreads();
  const int base = blockIdx.x * SORT_BS;
#pragma unroll
  for (int it = 0; it < SORT_BS / 512; ++it) {
    const int e = base + it * 512 + threadIdx.x;
    if (e < E) {
      const int d = dst[e], r = et[e];
      const int c = r * NN + d;                        // [R][N] layout
      atomicAdd(&cnt32[c >> 1], 1u << (16 * (c & 1))); // 16-bit halfword bump
      atomicAdd(&lh[r], 1);                            // LDS
    }
  }
  __syncthreads();
  if (threadIdx.x < RR) bhist[blockIdx.x * RR + threadIdx.x] = lh[threadIdx.x];
}

// ---- fused scanA: [deg-from-cnt block-reduce | per-relation block prefix] ----

__global__ __launch_bounds__(1024) void scanA_k(const unsigned short* __restrict__ c16,
                                                int* __restrict__ deg,
                                                int* __restrict__ bsum,
                                                const int* __restrict__ bhist,
                                                int* __restrict__ boffrel,
                                                int* __restrict__ total) {
  __shared__ int s[SCAN_BS];
  const int t = threadIdx.x;
  if (blockIdx.x < SCAN_NB) {
    const int idx = blockIdx.x * SCAN_BS + t;
    int d = 0;
    if (idx < NN) {
#pragma unroll 13
      for (int r = 0; r < RR; ++r) d += c16[r * NN + idx];  // coalesced 2B
      deg[idx] = d;
    }
    s[t] = d;
    __syncthreads();
    for (int off = SCAN_BS / 2; off > 0; off >>= 1) {
      if (t < off) s[t] += s[t + off];
      __syncthreads();
    }
    if (t == 0) bsum[blockIdx.x] = s[0];
  } else {
    const int r = blockIdx.x - SCAN_NB;        // relation
    const int v = (t < NSB) ? bhist[t * RR + r] : 0;
    s[t] = v;
    __syncthreads();
    for (int off = 1; off < SCAN_BS; off <<= 1) {
      const int u = (t >= off) ? s[t - off] : 0;
      __syncthreads();
      s[t] += u;
      __syncthreads();
    }
    if (t < NSB) boffrel[t * RR + r] = s[t] - v;   // exclusive within relation
    if (t == SCAN_BS - 1) total[r] = s[SCAN_BS - 1];
  }
}

// ---- fused scanB: [wave-scan bsum | type totals -> tptr + chunks] ----

__global__ __launch_bounds__(128) void scanB_k(int* __restrict__ bsum,
                                               const int* __restrict__ total,
                                               int* __restrict__ tptrg,
                                               int4* __restrict__ chunkArr,
                                               int* __restrict__ nchunks) {
  const int t = threadIdx.x;
  if (blockIdx.x == 0) {
    if (t < 64) {
      int v = (t < SCAN_NB) ? bsum[t] : 0;
      const int orig = v;
      for (int off = 1; off < 64; off <<= 1) {
        const int u = __shfl_up(v, off, 64);
        if (t >= off) v += u;
      }
      if (t < SCAN_NB) bsum[t] = v - orig;   // exclusive
    }
  } else {
    __shared__ int tptr[RR + 1], chbase[RR + 1];
    if (t == 0) {
      int run = 0, crun = 0;
      for (int r = 0; r < RR; ++r) {
        tptr[r] = run;    run  += total[r];
        chbase[r] = crun; crun += (total[r] + CHUNK - 1) / CHUNK;
      }
      tptr[RR] = run; chbase[RR] = crun;
      *nchunks = crun;
    }
    __syncthreads();
    if (t < RR) {
      tptrg[t] = tptr[t];
      const int tot = total[t];
      const int nc = (tot + CHUNK - 1) / CHUNK;
      for (int i = 0; i < nc; ++i) {
        const int beg = tptr[t] + i * CHUNK;
        chunkArr[chbase[t] + i] = make_int4(beg, min(beg + CHUNK, tptr[t] + tot), t, 0);
      }
    }
  }
}

__global__ __launch_bounds__(1024) void scan3_k(const int* __restrict__ deg,
                                                const int* __restrict__ bsum,
                                                int* __restrict__ rowptr,
                                                int* __restrict__ poscur) {
  __shared__ int s[SCAN_BS];
  const int t = threadIdx.x;
  const int idx = blockIdx.x * SCAN_BS + t;
  const int v = (idx < NN) ? deg[idx] : 0;
  s[t] = v;
  __syncthreads();
  for (int off = 1; off < SCAN_BS; off <<= 1) {  // Hillis-Steele inclusive
    const int u = (t >= off) ? s[t - off] : 0;
    __syncthreads();
    s[t] += u;
    __syncthreads();
  }
  const int excl = bsum[blockIdx.x] + s[t] - v;
  if (idx < NN) { rowptr[idx] = excl; poscur[idx] = excl; }
  if (idx == NN - 1) rowptr[NN] = EE;
}

__global__ __launch_bounds__(512) void scatter_k(const int* __restrict__ src,
                                                 const int* __restrict__ dst,
                                                 const int* __restrict__ et,
                                                 const unsigned short* __restrict__ c16,
                                                 const int* __restrict__ boffrel,
                                                 const int* __restrict__ tptrg,
                                                 int* __restrict__ poscur,
                                                 int* __restrict__ osrc,
                                                 int* __restrict__ opos,
                                                 float* __restrict__ oscale, int E) {
  __shared__ int cur[RR];
  if (threadIdx.x < RR)
    cur[threadIdx.x] = tptrg[threadIdx.x] + boffrel[blockIdx.x * RR + threadIdx.x];
  __syncthreads();
  const int base = blockIdx.x * SORT_BS;
#pragma unroll
  for (int it = 0; it < SORT_BS / 512; ++it) {
    const int e = base + it * 512 + threadIdx.x;
    if (e < E) {
      const int s = src[e], d = dst[e], r = et[e];
      const int q = atomicAdd(&cur[r], 1);       // LDS atomic, block-local
      const int p = atomicAdd(&poscur[d], 1);    // global, ~12 avg contention
      osrc[q] = s;
      opos[q] = p;
      oscale[q] = 1.0f / (float)c16[r * NN + d]; // 2B random read, L2-resident
    }
  }
}

// ---------------- per-layer kernels ----------------

// MFMA message kernel: one block per 256-edge relation-chunk, 4 waves x 64 edges.
__global__ __launch_bounds__(256) void msgm_k(const unsigned short* __restrict__ hbf,
                                              const int* __restrict__ osrc,
                                              const int* __restrict__ opos,
                                              const float* __restrict__ oscale,
                                              const unsigned short* __restrict__ WT,
                                              const int4* __restrict__ chunkArr,
                                              const int* __restrict__ nchunks,
                                              unsigned short* __restrict__ m) {
  const int ci = blockIdx.x;
  if (ci >= *nchunks) return;
  const int4 c = chunkArr[ci];
  const int beg = c.x, end = c.y, rel = c.z;

  __shared__ unsigned short Wl[DIM][72];   // +8 pad
  {
    const float4* s4 = reinterpret_cast<const float4*>(WT + (size_t)rel * 4096);
#pragma unroll
    for (int it = 0; it < 2; ++it) {
      const int seg = threadIdx.x + it * 256;   // 512 x 16B segments
      const int row = seg >> 3, s8 = seg & 7;
      *reinterpret_cast<float4*>(&Wl[row][s8 * 8]) = s4[seg];
    }
  }
  __syncthreads();

  const int w  = threadIdx.x >> 6;
  const int l  = threadIdx.x & 63;
  const int lr = l & 15, lq = l >> 4;

  const int ebase = beg + w * 64;
  if (ebase >= end) return;                // no barriers after this point

  short8v a[4][2];
#pragma unroll
  for (int ct = 0; ct < 4; ++ct)
#pragma unroll
    for (int kk = 0; kk < 2; ++kk)
      a[ct][kk] = *reinterpret_cast<const short8v*>(&Wl[ct * 16 + lr][kk * 32 + lq * 8]);

  short8v b[4][2];
  int eidx[4];
#pragma unroll
  for (int et = 0; et < 4; ++et) {
    eidx[et] = ebase + et * 16 + lr;
    const int e = min(eidx[et], end - 1);  // clamp (safe dup, store guarded)
    const int s = osrc[e];
    const unsigned short* hp = hbf + (size_t)s * DIM;
    b[et][0] = *reinterpret_cast<const short8v*>(hp + lq * 8);
    b[et][1] = *reinterpret_cast<const short8v*>(hp + 32 + lq * 8);
  }

  floatx4 acc[4][4];
#pragma unroll
  for (int ct = 0; ct < 4; ++ct)
#pragma unroll
    for (int et = 0; et < 4; ++et)
      acc[ct][et] = (floatx4){0.f, 0.f, 0.f, 0.f};

#pragma unroll
  for (int kk = 0; kk < 2; ++kk)
#pragma unroll
    for (int ct = 0; ct < 4; ++ct)
#pragma unroll
      for (int et = 0; et < 4; ++et)
        acc[ct][et] = __builtin_amdgcn_mfma_f32_16x16x32_bf16(a[ct][kk], b[et][kk],
                                                              acc[ct][et], 0, 0, 0);

#pragma unroll
  for (int et = 0; et < 4; ++et) {
    const int e = eidx[et];
    if (e < end) {
      const float sc = oscale[e];
      unsigned short* op = m + (size_t)opos[e] * DIM;
#pragma unroll
      for (int ct = 0; ct < 4; ++ct) {
        ushort4 o;
        o.x = f2bf(acc[ct][et][0] * sc);
        o.y = f2bf(acc[ct][et][1] * sc);
        o.z = f2bf(acc[ct][et][2] * sc);
        o.w = f2bf(acc[ct][et][3] * sc);
        *reinterpret_cast<ushort4*>(op + ct * 16 + lq * 4) = o;
      }
    }
  }
}

// Dense node transform: rt16 = bf16(h@root + b), rs16 = bf16(relu(h@rw + rb)).
template<bool F32SRC>
__global__ __launch_bounds__(256) void xform_k(const void* __restrict__ hsrc,
                                               const float* __restrict__ root,
                                               const float* __restrict__ bias,
                                               const float* __restrict__ rw,
                                               const float* __restrict__ rb,
                                               unsigned short* __restrict__ rt16,
                                               unsigned short* __restrict__ rs16, int N) {
  __shared__ float Wl0[DIM * DIM];
  __shared__ float Wl1[DIM * DIM];
  __shared__ float xs[XNB][68];
#pragma unroll
  for (int i = 0; i < 4; ++i) {
    reinterpret_cast<float4*>(Wl0)[threadIdx.x + i * 256] =
        reinterpret_cast<const float4*>(root)[threadIdx.x + i * 256];
    reinterpret_cast<float4*>(Wl1)[threadIdx.x + i * 256] =
        reinterpret_cast<const float4*>(rw)[threadIdx.x + i * 256];
  }

  const int g = threadIdx.x >> 4, li = threadIdx.x & 15;
  const int base = blockIdx.x * XNB;
#pragma unroll
  for (int r = 0; r < 4; ++r) {
    const int n = base + g * 4 + r;
    float4 v = make_float4(0.f, 0.f, 0.f, 0.f);
    if (n < N) {
      if (F32SRC) {
        v = *reinterpret_cast<const float4*>((const float*)hsrc + (size_t)n * DIM + li * 4);
      } else {
        const ushort4 u = *reinterpret_cast<const ushort4*>(
            (const unsigned short*)hsrc + (size_t)n * DIM + li * 4);
        v = make_float4(bf2f(u.x), bf2f(u.y), bf2f(u.z), bf2f(u.w));
      }
    }
    *reinterpret_cast<float4*>(&xs[g * 4 + r][li * 4]) = v;
  }
  __syncthreads();

  float aR[4][4], aS[4][4];
#pragma unroll
  for (int r = 0; r < 4; ++r)
#pragma unroll
    for (int q = 0; q < 4; ++q) { aR[r][q] = 0.f; aS[r][q] = 0.f; }

#pragma unroll 4
  for (int k = 0; k < DIM; ++k) {
    const float4 wr = *reinterpret_cast<const float4*>(&Wl0[k * DIM + li * 4]);
    const float4 wv = *reinterpret_cast<const float4*>(&Wl1[k * DIM + li * 4]);
#pragma unroll
    for (int r = 0; r < 4; ++r) {
      const float xv = xs[g * 4 + r][k];
      aR[r][0] += xv * wr.x; aR[r][1] += xv * wr.y; aR[r][2] += xv * wr.z; aR[r][3] += xv * wr.w;
      aS[r][0] += xv * wv.x; aS[r][1] += xv * wv.y; aS[r][2] += xv * wv.z; aS[r][3] += xv * wv.w;
    }
  }

  const float4 bv = reinterpret_cast<const float4*>(bias)[li];
  const float4 cv = reinterpret_cast<const float4*>(rb)[li];
#pragma unroll
  for (int r = 0; r < 4; ++r) {
    const int n = base + g * 4 + r;
    if (n < N) {
      ushort4 t, s;
      t.x = f2bf(aR[r][0] + bv.x); t.y = f2bf(aR[r][1] + bv.y);
      t.z = f2bf(aR[r][2] + bv.z); t.w = f2bf(aR[r][3] + bv.w);
      s.x = f2bf(fmaxf(aS[r][0] + cv.x, 0.f)); s.y = f2bf(fmaxf(aS[r][1] + cv.y, 0.f));
      s.z = f2bf(fmaxf(aS[r][2] + cv.z, 0.f)); s.w = f2bf(fmaxf(aS[r][3] + cv.w, 0.f));
      *reinterpret_cast<ushort4*>(rt16 + (size_t)n * DIM + li * 4) = t;
      *reinterpret_cast<ushort4*>(rs16 + (size_t)n * DIM + li * 4) = s;
    }
  }
}

// Streaming epilogue: out = relu(sum(msgs) + rt) + rs. Output bf16 (next h) or f32.
template<bool OUT_BF16>
__global__ __launch_bounds__(256) void gather2_k(const unsigned short* __restrict__ m,
                                                 const int* __restrict__ rowptr,
                                                 const unsigned short* __restrict__ rt16,
                                                 const unsigned short* __restrict__ rs16,
                                                 void* __restrict__ hout, int N) {
  const int g = threadIdx.x >> 4, li = threadIdx.x & 15;
  const int n = blockIdx.x * 16 + g;
  if (n >= N) return;

  float a0 = 0.f, a1 = 0.f, a2 = 0.f, a3 = 0.f;
  const int jb = rowptr[n], je = rowptr[n + 1];
  int j = jb;
  for (; j + 8 <= je; j += 8) {            // 8 independent loads in flight
    ushort4 v[8];
#pragma unroll
    for (int u = 0; u < 8; ++u)
      v[u] = *reinterpret_cast<const ushort4*>(m + (size_t)(j + u) * DIM + li * 4);
#pragma unroll
    for (int u = 0; u < 8; ++u) {
      a0 += bf2f(v[u].x); a1 += bf2f(v[u].y); a2 += bf2f(v[u].z); a3 += bf2f(v[u].w);
    }
  }
  for (; j + 4 <= je; j += 4) {
    ushort4 v[4];
#pragma unroll
    for (int u = 0; u < 4; ++u)
      v[u] = *reinterpret_cast<const ushort4*>(m + (size_t)(j + u) * DIM + li * 4);
#pragma unroll
    for (int u = 0; u < 4; ++u) {
      a0 += bf2f(v[u].x); a1 += bf2f(v[u].y); a2 += bf2f(v[u].z); a3 += bf2f(v[u].w);
    }
  }
  for (; j < je; ++j) {
    const ushort4 v = *reinterpret_cast<const ushort4*>(m + (size_t)j * DIM + li * 4);
    a0 += bf2f(v.x); a1 += bf2f(v.y); a2 += bf2f(v.z); a3 += bf2f(v.w);
  }

  const ushort4 tu = *reinterpret_cast<const ushort4*>(rt16 + (size_t)n * DIM + li * 4);
  const ushort4 su = *reinterpret_cast<const ushort4*>(rs16 + (size_t)n * DIM + li * 4);
  const float o0 = fmaxf(a0 + bf2f(tu.x), 0.f) + bf2f(su.x);
  const float o1 = fmaxf(a1 + bf2f(tu.y), 0.f) + bf2f(su.y);
  const float o2 = fmaxf(a2 + bf2f(tu.z), 0.f) + bf2f(su.z);
  const float o3 = fmaxf(a3 + bf2f(tu.w), 0.f) + bf2f(su.w);
  if (OUT_BF16) {
    ushort4 o;
    o.x = f2bf(o0); o.y = f2bf(o1); o.z = f2bf(o2); o.w = f2bf(o3);
    *reinterpret_cast<ushort4*>((unsigned short*)hout + (size_t)n * DIM + li * 4) = o;
  } else {
    *reinterpret_cast<float4*>((float*)hout + (size_t)n * DIM + li * 4) =
        make_float4(o0, o1, o2, o3);
  }
}

// ---------------- last-resort fallback (float atomics, self-contained) ----------------

__global__ __launch_bounds__(256) void count_k(const int* __restrict__ dst,
                                               const int* __restrict__ et,
                                               int* __restrict__ cnt, int E) {
  int e = blockIdx.x * 256 + threadIdx.x;
  if (e < E) atomicAdd(&cnt[dst[e] * RR + et[e]], 1);
}

__global__ __launch_bounds__(256) void edge_k(const float* __restrict__ h,
                                              const int* __restrict__ src,
                                              const int* __restrict__ dst,
                                              const int* __restrict__ et,
                                              const float* __restrict__ W,
                                              const int* __restrict__ cnt,
                                              float* __restrict__ accum, int E) {
  __shared__ float xs[16][68];
  const int g = threadIdx.x >> 4, li = threadIdx.x & 15;
  const int e = blockIdx.x * 16 + g;
  if (e >= E) return;
  const int s = src[e], d = dst[e], t = et[e];
  *reinterpret_cast<float4*>(&xs[g][li * 4]) =
      *reinterpret_cast<const float4*>(h + (size_t)s * DIM + li * 4);
  const float* Wt = W + (size_t)t * (DIM * DIM) + li * 4;
  float a0 = 0.f, a1 = 0.f, a2 = 0.f, a3 = 0.f;
#pragma unroll 8
  for (int k = 0; k < DIM; ++k) {
    const float xd = xs[g][k];
    const float4 w = *reinterpret_cast<const float4*>(Wt + k * DIM);
    a0 += xd * w.x; a1 += xd * w.y; a2 += xd * w.z; a3 += xd * w.w;
  }
  const float sc = 1.0f / (float)cnt[d * RR + t];
  float* o = accum + (size_t)d * DIM + li * 4;
  unsafeAtomicAdd(o + 0, a0 * sc);
  unsafeAtomicAdd(o + 1, a1 * sc);
  unsafeAtomicAdd(o + 2, a2 * sc);
  unsafeAtomicAdd(o + 3, a3 * sc);
}

__global__ __launch_bounds__(256) void node_k(const float* __restrict__ h,
                                              const float* __restrict__ root,
                                              const float* __restrict__ bias,
                                              const float* __restrict__ rw,
                                              const float* __restrict__ rb,
                                              float* __restrict__ io, int N) {
  __shared__ float xs[16][68];
  const int g = threadIdx.x >> 4, li = threadIdx.x & 15;
  const int n = blockIdx.x * 16 + g;
  if (n >= N) return;
  *reinterpret_cast<float4*>(&xs[g][li * 4]) =
      *reinterpret_cast<const float4*>(h + (size_t)n * DIM + li * 4);
  float r0 = 0.f, r1 = 0.f, r2 = 0.f, r3 = 0.f;
  float s0 = 0.f, s1 = 0.f, s2 = 0.f, s3 = 0.f;
#pragma unroll 8
  for (int k = 0; k < DIM; ++k) {
    const float hd = xs[g][k];
    const float4 w = *reinterpret_cast<const float4*>(root + k * DIM + li * 4);
    const float4 v = *reinterpret_cast<const float4*>(rw + k * DIM + li * 4);
    r0 += hd * w.x; r1 += hd * w.y; r2 += hd * w.z; r3 += hd * w.w;
    s0 += hd * v.x; s1 += hd * v.y; s2 += hd * v.z; s3 += hd * v.w;
  }
  float* o = io + (size_t)n * DIM + li * 4;
  const float4 acc = *reinterpret_cast<const float4*>(o);
  const float4 b = *reinterpret_cast<const float4*>(bias + li * 4);
  const float4 c = *reinterpret_cast<const float4*>(rb + li * 4);
  float o0 = fmaxf(acc.x + r0 + b.x, 0.f) + fmaxf(s0 + c.x, 0.f);
  float o1 = fmaxf(acc.y + r1 + b.y, 0.f) + fmaxf(s1 + c.y, 0.f);
  float o2 = fmaxf(acc.z + r2 + b.z, 0.f) + fmaxf(s2 + c.z, 0.f);
  float o3 = fmaxf(acc.w + r3 + b.w, 0.f) + fmaxf(s3 + c.w, 0.f);
  *reinterpret_cast<float4*>(o) = make_float4(o0, o1, o2, o3);
}

// ---------------- host ----------------

extern "C" void kernel_launch(void* const* d_in, const int* in_sizes, int n_in,
                              void* d_out, int out_size, void* d_ws, size_t ws_size,
                              hipStream_t stream) {
  const float* x    = (const float*)d_in[0];
  const int*   ei   = (const int*)d_in[1];
  const int*   et   = (const int*)d_in[2];
  const float* W    = (const float*)d_in[3];
  const float* root = (const float*)d_in[4];
  const float* bias = (const float*)d_in[5];
  const float* resW = (const float*)d_in[6];
  const float* resb = (const float*)d_in[7];
  float* out = (float*)d_out;

  const int* src = ei;
  const int* dstp = ei + EE;

  char* ws = (char*)d_ws;
  size_t off = 0;
  auto take = [&](size_t bytes) -> void* {
    void* p = ws + off;
    off = (off + bytes + 255) & ~(size_t)255;
    return p;
  };
  unsigned short* m = (unsigned short*)take((size_t)EE * DIM * sizeof(unsigned short));
  int* deg       = (int*)take((size_t)NN * sizeof(int));
  int* rowptr    = (int*)take((size_t)(NN + 1) * sizeof(int));
  int* poscur    = (int*)take((size_t)NN * sizeof(int));
  int* bhist     = (int*)take((size_t)NSB * RR * sizeof(int));
  int* boffrel   = (int*)take((size_t)NSB * RR * sizeof(int));
  int* total     = (int*)take((size_t)RR * sizeof(int));
  int* tptrg     = (int*)take((size_t)RR * sizeof(int));
  int* bsum      = (int*)take((size_t)SCAN_NB * sizeof(int));
  int* osrc      = (int*)take((size_t)EE * sizeof(int));
  int* opos      = (int*)take((size_t)EE * sizeof(int));
  float* oscale  = (float*)take((size_t)EE * sizeof(float));
  int4* chunkArr = (int4*)take((size_t)MAXCHUNKS * sizeof(int4));
  int* nchunks   = (int*)take(256);
  unsigned short* rt16 = (unsigned short*)take((size_t)NN * DIM * sizeof(unsigned short));
  unsigned short* rs16 = (unsigned short*)take((size_t)NN * DIM * sizeof(unsigned short));
  unsigned short* hbf  = (unsigned short*)take((size_t)NN * DIM * sizeof(unsigned short));
  unsigned short* wbt  = (unsigned short*)take((size_t)2 * RR * DIM * DIM * sizeof(unsigned short));
  const size_t main_off = off;
  unsigned int* cnt32 = (unsigned int*)m;           // alias: uint16[R][N] = 6.5MB
  const unsigned short* c16 = (const unsigned short*)m;

  if (main_off <= ws_size) {
    // 1: fused setup (zero cnt | W->bf16^T | x->bf16)
    setup_k<<<ZB + CB + HB, 256, 0, stream>>>((int4*)cnt32, W, wbt, x, hbf);
    // 2: histograms
    hist_k<<<NSB, 512, 0, stream>>>(dstp, et, cnt32, bhist, EE);
    // 3: [deg reduce | per-relation prefix]
    scanA_k<<<SCAN_NB + RR, 1024, 0, stream>>>(c16, deg, bsum, bhist, boffrel, total);
    // 4: [bsum scan | type totals -> chunks]
    scanB_k<<<2, 128, 0, stream>>>(bsum, total, tptrg, chunkArr, nchunks);
    // 5: node rowptr
    scan3_k<<<SCAN_NB, 1024, 0, stream>>>(deg, bsum, rowptr, poscur);
    // 6: edge scatter
    scatter_k<<<NSB, 512, 0, stream>>>(src, dstp, et, c16, boffrel, tptrg, poscur,
                                       osrc, opos, oscale, EE);

    const int XG = (NN + XNB - 1) / XNB;
    // layer 0: x -> hbf(h1)
    xform_k<true><<<XG, 256, 0, stream>>>(x, root, bias, resW, resb, rt16, rs16, NN);
    msgm_k<<<MAXCHUNKS, 256, 0, stream>>>(hbf, osrc, opos, oscale, wbt, chunkArr, nchunks, m);
    gather2_k<true><<<(NN + 15) / 16, 256, 0, stream>>>(m, rowptr, rt16, rs16, hbf, NN);
    // layer 1: hbf(h1) -> out (f32)
    xform_k<false><<<XG, 256, 0, stream>>>(hbf, root + DIM * DIM, bias + DIM,
                                           resW + DIM * DIM, resb + DIM, rt16, rs16, NN);
    msgm_k<<<MAXCHUNKS, 256, 0, stream>>>(hbf, osrc, opos, oscale,
                                          wbt + (size_t)RR * DIM * DIM, chunkArr, nchunks, m);
    gather2_k<false><<<(NN + 15) / 16, 256, 0, stream>>>(m, rowptr, rt16, rs16, out, NN);
  } else {
    // ---- fallback: atomic path (needs only 25.8 MB) ----
    int* fcnt = (int*)ws;
    float* fh1 = (float*)(ws + (size_t)NN * RR * sizeof(int));
    hipMemsetAsync(fcnt, 0, (size_t)NN * RR * sizeof(int), stream);
    hipMemsetAsync(fh1, 0, (size_t)NN * DIM * sizeof(float), stream);
    hipMemsetAsync(out, 0, (size_t)NN * DIM * sizeof(float), stream);
    count_k<<<(EE + 255) / 256, 256, 0, stream>>>(dstp, et, fcnt, EE);
    edge_k<<<(EE + 15) / 16, 256, 0, stream>>>(x, src, dstp, et, W, fcnt, fh1, EE);
    node_k<<<(NN + 15) / 16, 256, 0, stream>>>(x, root, bias, resW, resb, fh1, NN);
    edge_k<<<(EE + 15) / 16, 256, 0, stream>>>(fh1, src, dstp, et,
                                               W + (size_t)RR * DIM * DIM, fcnt, out, EE);
    node_k<<<(NN + 15) / 16, 256, 0, stream>>>(fh1, root + DIM * DIM, bias + DIM,
                                               resW + DIM * DIM, resb + DIM, out, NN);
  }
}

// Round 14
// 224.382 us; speedup vs baseline: 1.2574x; 1.0056x over previous
//
#include <hip/hip_runtime.h>

// RGCN: N=50000, E=600000, D=64, R=65, L=2.
// out_i = relu( sum_r mean_{j in N_r(i)} x_j@W_r + x_i@root + b ) + relu( x_i@res_W + res_b )
// Counting-sort pipeline (relation-sort -> MFMA W reuse; dst-sort -> CSR gather).
// Round-14: SORT_BS 1024->512 (1172 hist/scatter blocks): these kernels are
// random-access latency-bound; each halving of block size has bought ~5us by
// doubling outstanding misses. scanA per-relation prefix now 2-items/thread.

constexpr int NN  = 50000;
constexpr int EE  = 600000;
constexpr int DIM = 64;
constexpr int RR  = 65;
constexpr int CHUNK = 256;                        // edges per msgm relation-chunk
constexpr int MAXCHUNKS = EE / CHUNK + RR + 8;
constexpr int SORT_BS = 512;                      // edges per sort block
constexpr int NSB = (EE + SORT_BS - 1) / SORT_BS; // 1172
constexpr int SCAN_BS = 1024;
constexpr int SCAN_NB = (NN + SCAN_BS - 1) / SCAN_BS; // 49
constexpr int XNB = 64;                           // nodes per xform block

typedef __attribute__((ext_vector_type(8))) short short8v;
typedef __attribute__((ext_vector_type(4))) float floatx4;

__device__ inline unsigned short f2bf(float f) {
  unsigned int u = __float_as_uint(f);
  return (unsigned short)((u + 0x7fffu + ((u >> 16) & 1u)) >> 16);  // RNE
}
__device__ inline float bf2f(unsigned short v) {
  return __uint_as_float(((unsigned int)v) << 16);
}

// ---------------- fused setup kernel: zero cnt | cvt W | cvt x ----------------

constexpr int ZN4 = NN * RR * 2 / 16;             // int4 count of uint16 cnt (6.5MB)
constexpr int ZB  = (ZN4 + 255) / 256;
constexpr int CW4 = 2 * RR * DIM * DIM / 4;       // float4 count of W
constexpr int CB  = (CW4 + 255) / 256;
constexpr int HB  = (NN * DIM / 8 + 255) / 256;

__global__ __launch_bounds__(256) void setup_k(int4* __restrict__ zp,
                                               const float* __restrict__ W,
                                               unsigned short* __restrict__ WT,
                                               const float* __restrict__ x,
                                               unsigned short* __restrict__ hbf) {
  const int b = blockIdx.x;
  if (b < ZB) {
    const int i = b * 256 + threadIdx.x;
    if (i < ZN4) zp[i] = make_int4(0, 0, 0, 0);
  } else if (b < ZB + CB) {
    // W[l][r][k][c] f32 -> WT[l*R+r][c][k] bf16 (transposed)
    const int tid = (b - ZB) * 256 + threadIdx.x;
    if (tid >= CW4) return;
    const int base = tid * 4;
    const int mat = base >> 12, rem = base & 4095;
    const int k = rem >> 6, c0 = rem & 63;
    const float4 v = *reinterpret_cast<const float4*>(W + base);
    unsigned short* o = WT + (size_t)mat * 4096;
    o[(c0 + 0) * 64 + k] = f2bf(v.x);
    o[(c0 + 1) * 64 + k] = f2bf(v.y);
    o[(c0 + 2) * 64 + k] = f2bf(v.z);
    o[(c0 + 3) * 64 + k] = f2bf(v.w);
  } else {
    const int tid = (b - ZB - CB) * 256 + threadIdx.x;   // 8 elems per thread
    if (tid * 8 >= NN * DIM) return;
    const float4 v0 = reinterpret_cast<const float4*>(x)[tid * 2];
    const float4 v1 = reinterpret_cast<const float4*>(x)[tid * 2 + 1];
    ushort4 a, c;
    a.x = f2bf(v0.x); a.y = f2bf(v0.y); a.z = f2bf(v0.z); a.w = f2bf(v0.w);
    c.x = f2bf(v1.x); c.y = f2bf(v1.y); c.z = f2bf(v1.z); c.w = f2bf(v1.w);
    reinterpret_cast<ushort4*>(hbf)[tid * 2] = a;
    reinterpret_cast<ushort4*>(hbf)[tid * 2 + 1] = c;
  }
}

// Fused: uint16 (d,r)-histogram via packed 32-bit atomics + per-block LDS type hist.
__global__ __launch_bounds__(512) void hist_k(const int* __restrict__ dst,
                                              const int* __restrict__ et,
                                              unsigned int* __restrict__ cnt32,
                                              int* __restrict__ bhist, int E) {
  __shared__ int lh[RR];
  if (threadIdx.x < RR) lh[threadIdx.x] = 0;
  __syncthreads();
  const int e = blockIdx.x * SORT_BS + threadIdx.x;
  if (e < E) {
    const int d = dst[e], r = et[e];
    const int c = r * NN + d;                        // [R][N] layout
    atomicAdd(&cnt32[c >> 1], 1u << (16 * (c & 1))); // 16-bit halfword bump
    atomicAdd(&lh[r], 1);                            // LDS
  }
  __syncthreads();
  if (threadIdx.x < RR) bhist[blockIdx.x * RR + threadIdx.x] = lh[threadIdx.x];
}

// ---- fused scanA: [deg-from-cnt block-reduce | per-relation block prefix] ----
// Per-relation prefix handles NSB=1172 via 2 items per thread.

__global__ __launch_bounds__(1024) void scanA_k(const unsigned short* __restrict__ c16,
                                                int* __restrict__ deg,
                                                int* __restrict__ bsum,
                                                const int* __restrict__ bhist,
                                                int* __restrict__ boffrel,
                                                int* __restrict__ total) {
  __shared__ int s[SCAN_BS];
  const int t = threadIdx.x;
  if (blockIdx.x < SCAN_NB) {
    const int idx = blockIdx.x * SCAN_BS + t;
    int d = 0;
    if (idx < NN) {
#pragma unroll 13
      for (int r = 0; r < RR; ++r) d += c16[r * NN + idx];  // coalesced 2B
      deg[idx] = d;
    }
    s[t] = d;
    __syncthreads();
    for (int off = SCAN_BS / 2; off > 0; off >>= 1) {
      if (t < off) s[t] += s[t + off];
      __syncthreads();
    }
    if (t == 0) bsum[blockIdx.x] = s[0];
  } else {
    const int r = blockIdx.x - SCAN_NB;        // relation
    const int i0 = 2 * t, i1 = 2 * t + 1;
    const int v0 = (i0 < NSB) ? bhist[i0 * RR + r] : 0;
    const int v1 = (i1 < NSB) ? bhist[i1 * RR + r] : 0;
    s[t] = v0 + v1;
    __syncthreads();
    for (int off = 1; off < SCAN_BS; off <<= 1) {   // inclusive over pair-sums
      const int u = (t >= off) ? s[t - off] : 0;
      __syncthreads();
      s[t] += u;
      __syncthreads();
    }
    const int excl = s[t] - v0 - v1;                // exclusive before item i0
    if (i0 < NSB) boffrel[i0 * RR + r] = excl;
    if (i1 < NSB) boffrel[i1 * RR + r] = excl + v0;
    if (t == SCAN_BS - 1) total[r] = s[SCAN_BS - 1];
  }
}

// ---- fused scanB: [wave-scan bsum | type totals -> tptr + chunks] ----

__global__ __launch_bounds__(128) void scanB_k(int* __restrict__ bsum,
                                               const int* __restrict__ total,
                                               int* __restrict__ tptrg,
                                               int4* __restrict__ chunkArr,
                                               int* __restrict__ nchunks) {
  const int t = threadIdx.x;
  if (blockIdx.x == 0) {
    if (t < 64) {
      int v = (t < SCAN_NB) ? bsum[t] : 0;
      const int orig = v;
      for (int off = 1; off < 64; off <<= 1) {
        const int u = __shfl_up(v, off, 64);
        if (t >= off) v += u;
      }
      if (t < SCAN_NB) bsum[t] = v - orig;   // exclusive
    }
  } else {
    __shared__ int tptr[RR + 1], chbase[RR + 1];
    if (t == 0) {
      int run = 0, crun = 0;
      for (int r = 0; r < RR; ++r) {
        tptr[r] = run;    run  += total[r];
        chbase[r] = crun; crun += (total[r] + CHUNK - 1) / CHUNK;
      }
      tptr[RR] = run; chbase[RR] = crun;
      *nchunks = crun;
    }
    __syncthreads();
    if (t < RR) {
      tptrg[t] = tptr[t];
      const int tot = total[t];
      const int nc = (tot + CHUNK - 1) / CHUNK;
      for (int i = 0; i < nc; ++i) {
        const int beg = tptr[t] + i * CHUNK;
        chunkArr[chbase[t] + i] = make_int4(beg, min(beg + CHUNK, tptr[t] + tot), t, 0);
      }
    }
  }
}

__global__ __launch_bounds__(1024) void scan3_k(const int* __restrict__ deg,
                                                const int* __restrict__ bsum,
                                                int* __restrict__ rowptr,
                                                int* __restrict__ poscur) {
  __shared__ int s[SCAN_BS];
  const int t = threadIdx.x;
  const int idx = blockIdx.x * SCAN_BS + t;
  const int v = (idx < NN) ? deg[idx] : 0;
  s[t] = v;
  __syncthreads();
  for (int off = 1; off < SCAN_BS; off <<= 1) {  // Hillis-Steele inclusive
    const int u = (t >= off) ? s[t - off] : 0;
    __syncthreads();
    s[t] += u;
    __syncthreads();
  }
  const int excl = bsum[blockIdx.x] + s[t] - v;
  if (idx < NN) { rowptr[idx] = excl; poscur[idx] = excl; }
  if (idx == NN - 1) rowptr[NN] = EE;
}

__global__ __launch_bounds__(512) void scatter_k(const int* __restrict__ src,
                                                 const int* __restrict__ dst,
                                                 const int* __restrict__ et,
                                                 const unsigned short* __restrict__ c16,
                                                 const int* __restrict__ boffrel,
                                                 const int* __restrict__ tptrg,
                                                 int* __restrict__ poscur,
                                                 int* __restrict__ osrc,
                                                 int* __restrict__ opos,
                                                 float* __restrict__ oscale, int E) {
  __shared__ int cur[RR];
  if (threadIdx.x < RR)
    cur[threadIdx.x] = tptrg[threadIdx.x] + boffrel[blockIdx.x * RR + threadIdx.x];
  __syncthreads();
  const int e = blockIdx.x * SORT_BS + threadIdx.x;
  if (e < E) {
    const int s = src[e], d = dst[e], r = et[e];
    const int q = atomicAdd(&cur[r], 1);       // LDS atomic, block-local
    const int p = atomicAdd(&poscur[d], 1);    // global, ~12 avg contention
    osrc[q] = s;
    opos[q] = p;
    oscale[q] = 1.0f / (float)c16[r * NN + d]; // 2B random read, L2-resident
  }
}

// ---------------- per-layer kernels ----------------

// MFMA message kernel: one block per 256-edge relation-chunk, 4 waves x 64 edges.
__global__ __launch_bounds__(256) void msgm_k(const unsigned short* __restrict__ hbf,
                                              const int* __restrict__ osrc,
                                              const int* __restrict__ opos,
                                              const float* __restrict__ oscale,
                                              const unsigned short* __restrict__ WT,
                                              const int4* __restrict__ chunkArr,
                                              const int* __restrict__ nchunks,
                                              unsigned short* __restrict__ m) {
  const int ci = blockIdx.x;
  if (ci >= *nchunks) return;
  const int4 c = chunkArr[ci];
  const int beg = c.x, end = c.y, rel = c.z;

  __shared__ unsigned short Wl[DIM][72];   // +8 pad
  {
    const float4* s4 = reinterpret_cast<const float4*>(WT + (size_t)rel * 4096);
#pragma unroll
    for (int it = 0; it < 2; ++it) {
      const int seg = threadIdx.x + it * 256;   // 512 x 16B segments
      const int row = seg >> 3, s8 = seg & 7;
      *reinterpret_cast<float4*>(&Wl[row][s8 * 8]) = s4[seg];
    }
  }
  __syncthreads();

  const int w  = threadIdx.x >> 6;
  const int l  = threadIdx.x & 63;
  const int lr = l & 15, lq = l >> 4;

  const int ebase = beg + w * 64;
  if (ebase >= end) return;                // no barriers after this point

  short8v a[4][2];
#pragma unroll
  for (int ct = 0; ct < 4; ++ct)
#pragma unroll
    for (int kk = 0; kk < 2; ++kk)
      a[ct][kk] = *reinterpret_cast<const short8v*>(&Wl[ct * 16 + lr][kk * 32 + lq * 8]);

  short8v b[4][2];
  int eidx[4];
#pragma unroll
  for (int et = 0; et < 4; ++et) {
    eidx[et] = ebase + et * 16 + lr;
    const int e = min(eidx[et], end - 1);  // clamp (safe dup, store guarded)
    const int s = osrc[e];
    const unsigned short* hp = hbf + (size_t)s * DIM;
    b[et][0] = *reinterpret_cast<const short8v*>(hp + lq * 8);
    b[et][1] = *reinterpret_cast<const short8v*>(hp + 32 + lq * 8);
  }

  floatx4 acc[4][4];
#pragma unroll
  for (int ct = 0; ct < 4; ++ct)
#pragma unroll
    for (int et = 0; et < 4; ++et)
      acc[ct][et] = (floatx4){0.f, 0.f, 0.f, 0.f};

#pragma unroll
  for (int kk = 0; kk < 2; ++kk)
#pragma unroll
    for (int ct = 0; ct < 4; ++ct)
#pragma unroll
      for (int et = 0; et < 4; ++et)
        acc[ct][et] = __builtin_amdgcn_mfma_f32_16x16x32_bf16(a[ct][kk], b[et][kk],
                                                              acc[ct][et], 0, 0, 0);

#pragma unroll
  for (int et = 0; et < 4; ++et) {
    const int e = eidx[et];
    if (e < end) {
      const float sc = oscale[e];
      unsigned short* op = m + (size_t)opos[e] * DIM;
#pragma unroll
      for (int ct = 0; ct < 4; ++ct) {
        ushort4 o;
        o.x = f2bf(acc[ct][et][0] * sc);
        o.y = f2bf(acc[ct][et][1] * sc);
        o.z = f2bf(acc[ct][et][2] * sc);
        o.w = f2bf(acc[ct][et][3] * sc);
        *reinterpret_cast<ushort4*>(op + ct * 16 + lq * 4) = o;
      }
    }
  }
}

// Dense node transform: rt16 = bf16(h@root + b), rs16 = bf16(relu(h@rw + rb)).
template<bool F32SRC>
__global__ __launch_bounds__(256) void xform_k(const void* __restrict__ hsrc,
                                               const float* __restrict__ root,
                                               const float* __restrict__ bias,
                                               const float* __restrict__ rw,
                                               const float* __restrict__ rb,
                                               unsigned short* __restrict__ rt16,
                                               unsigned short* __restrict__ rs16, int N) {
  __shared__ float Wl0[DIM * DIM];
  __shared__ float Wl1[DIM * DIM];
  __shared__ float xs[XNB][68];
#pragma unroll
  for (int i = 0; i < 4; ++i) {
    reinterpret_cast<float4*>(Wl0)[threadIdx.x + i * 256] =
        reinterpret_cast<const float4*>(root)[threadIdx.x + i * 256];
    reinterpret_cast<float4*>(Wl1)[threadIdx.x + i * 256] =
        reinterpret_cast<const float4*>(rw)[threadIdx.x + i * 256];
  }

  const int g = threadIdx.x >> 4, li = threadIdx.x & 15;
  const int base = blockIdx.x * XNB;
#pragma unroll
  for (int r = 0; r < 4; ++r) {
    const int n = base + g * 4 + r;
    float4 v = make_float4(0.f, 0.f, 0.f, 0.f);
    if (n < N) {
      if (F32SRC) {
        v = *reinterpret_cast<const float4*>((const float*)hsrc + (size_t)n * DIM + li * 4);
      } else {
        const ushort4 u = *reinterpret_cast<const ushort4*>(
            (const unsigned short*)hsrc + (size_t)n * DIM + li * 4);
        v = make_float4(bf2f(u.x), bf2f(u.y), bf2f(u.z), bf2f(u.w));
      }
    }
    *reinterpret_cast<float4*>(&xs[g * 4 + r][li * 4]) = v;
  }
  __syncthreads();

  float aR[4][4], aS[4][4];
#pragma unroll
  for (int r = 0; r < 4; ++r)
#pragma unroll
    for (int q = 0; q < 4; ++q) { aR[r][q] = 0.f; aS[r][q] = 0.f; }

#pragma unroll 4
  for (int k = 0; k < DIM; ++k) {
    const float4 wr = *reinterpret_cast<const float4*>(&Wl0[k * DIM + li * 4]);
    const float4 wv = *reinterpret_cast<const float4*>(&Wl1[k * DIM + li * 4]);
#pragma unroll
    for (int r = 0; r < 4; ++r) {
      const float xv = xs[g * 4 + r][k];
      aR[r][0] += xv * wr.x; aR[r][1] += xv * wr.y; aR[r][2] += xv * wr.z; aR[r][3] += xv * wr.w;
      aS[r][0] += xv * wv.x; aS[r][1] += xv * wv.y; aS[r][2] += xv * wv.z; aS[r][3] += xv * wv.w;
    }
  }

  const float4 bv = reinterpret_cast<const float4*>(bias)[li];
  const float4 cv = reinterpret_cast<const float4*>(rb)[li];
#pragma unroll
  for (int r = 0; r < 4; ++r) {
    const int n = base + g * 4 + r;
    if (n < N) {
      ushort4 t, s;
      t.x = f2bf(aR[r][0] + bv.x); t.y = f2bf(aR[r][1] + bv.y);
      t.z = f2bf(aR[r][2] + bv.z); t.w = f2bf(aR[r][3] + bv.w);
      s.x = f2bf(fmaxf(aS[r][0] + cv.x, 0.f)); s.y = f2bf(fmaxf(aS[r][1] + cv.y, 0.f));
      s.z = f2bf(fmaxf(aS[r][2] + cv.z, 0.f)); s.w = f2bf(fmaxf(aS[r][3] + cv.w, 0.f));
      *reinterpret_cast<ushort4*>(rt16 + (size_t)n * DIM + li * 4) = t;
      *reinterpret_cast<ushort4*>(rs16 + (size_t)n * DIM + li * 4) = s;
    }
  }
}

// Streaming epilogue: out = relu(sum(msgs) + rt) + rs. Output bf16 (next h) or f32.
template<bool OUT_BF16>
__global__ __launch_bounds__(256) void gather2_k(const unsigned short* __restrict__ m,
                                                 const int* __restrict__ rowptr,
                                                 const unsigned short* __restrict__ rt16,
                                                 const unsigned short* __restrict__ rs16,
                                                 void* __restrict__ hout, int N) {
  const int g = threadIdx.x >> 4, li = threadIdx.x & 15;
  const int n = blockIdx.x * 16 + g;
  if (n >= N) return;

  float a0 = 0.f, a1 = 0.f, a2 = 0.f, a3 = 0.f;
  const int jb = rowptr[n], je = rowptr[n + 1];
  int j = jb;
  for (; j + 8 <= je; j += 8) {            // 8 independent loads in flight
    ushort4 v[8];
#pragma unroll
    for (int u = 0; u < 8; ++u)
      v[u] = *reinterpret_cast<const ushort4*>(m + (size_t)(j + u) * DIM + li * 4);
#pragma unroll
    for (int u = 0; u < 8; ++u) {
      a0 += bf2f(v[u].x); a1 += bf2f(v[u].y); a2 += bf2f(v[u].z); a3 += bf2f(v[u].w);
    }
  }
  for (; j + 4 <= je; j += 4) {
    ushort4 v[4];
#pragma unroll
    for (int u = 0; u < 4; ++u)
      v[u] = *reinterpret_cast<const ushort4*>(m + (size_t)(j + u) * DIM + li * 4);
#pragma unroll
    for (int u = 0; u < 4; ++u) {
      a0 += bf2f(v[u].x); a1 += bf2f(v[u].y); a2 += bf2f(v[u].z); a3 += bf2f(v[u].w);
    }
  }
  for (; j < je; ++j) {
    const ushort4 v = *reinterpret_cast<const ushort4*>(m + (size_t)j * DIM + li * 4);
    a0 += bf2f(v.x); a1 += bf2f(v.y); a2 += bf2f(v.z); a3 += bf2f(v.w);
  }

  const ushort4 tu = *reinterpret_cast<const ushort4*>(rt16 + (size_t)n * DIM + li * 4);
  const ushort4 su = *reinterpret_cast<const ushort4*>(rs16 + (size_t)n * DIM + li * 4);
  const float o0 = fmaxf(a0 + bf2f(tu.x), 0.f) + bf2f(su.x);
  const float o1 = fmaxf(a1 + bf2f(tu.y), 0.f) + bf2f(su.y);
  const float o2 = fmaxf(a2 + bf2f(tu.z), 0.f) + bf2f(su.z);
  const float o3 = fmaxf(a3 + bf2f(tu.w), 0.f) + bf2f(su.w);
  if (OUT_BF16) {
    ushort4 o;
    o.x = f2bf(o0); o.y = f2bf(o1); o.z = f2bf(o2); o.w = f2bf(o3);
    *reinterpret_cast<ushort4*>((unsigned short*)hout + (size_t)n * DIM + li * 4) = o;
  } else {
    *reinterpret_cast<float4*>((float*)hout + (size_t)n * DIM + li * 4) =
        make_float4(o0, o1, o2, o3);
  }
}

// ---------------- last-resort fallback (float atomics, self-contained) ----------------

__global__ __launch_bounds__(256) void count_k(const int* __restrict__ dst,
                                               const int* __restrict__ et,
                                               int* __restrict__ cnt, int E) {
  int e = blockIdx.x * 256 + threadIdx.x;
  if (e < E) atomicAdd(&cnt[dst[e] * RR + et[e]], 1);
}

__global__ __launch_bounds__(256) void edge_k(const float* __restrict__ h,
                                              const int* __restrict__ src,
                                              const int* __restrict__ dst,
                                              const int* __restrict__ et,
                                              const float* __restrict__ W,
                                              const int* __restrict__ cnt,
                                              float* __restrict__ accum, int E) {
  __shared__ float xs[16][68];
  const int g = threadIdx.x >> 4, li = threadIdx.x & 15;
  const int e = blockIdx.x * 16 + g;
  if (e >= E) return;
  const int s = src[e], d = dst[e], t = et[e];
  *reinterpret_cast<float4*>(&xs[g][li * 4]) =
      *reinterpret_cast<const float4*>(h + (size_t)s * DIM + li * 4);
  const float* Wt = W + (size_t)t * (DIM * DIM) + li * 4;
  float a0 = 0.f, a1 = 0.f, a2 = 0.f, a3 = 0.f;
#pragma unroll 8
  for (int k = 0; k < DIM; ++k) {
    const float xd = xs[g][k];
    const float4 w = *reinterpret_cast<const float4*>(Wt + k * DIM);
    a0 += xd * w.x; a1 += xd * w.y; a2 += xd * w.z; a3 += xd * w.w;
  }
  const float sc = 1.0f / (float)cnt[d * RR + t];
  float* o = accum + (size_t)d * DIM + li * 4;
  unsafeAtomicAdd(o + 0, a0 * sc);
  unsafeAtomicAdd(o + 1, a1 * sc);
  unsafeAtomicAdd(o + 2, a2 * sc);
  unsafeAtomicAdd(o + 3, a3 * sc);
}

__global__ __launch_bounds__(256) void node_k(const float* __restrict__ h,
                                              const float* __restrict__ root,
                                              const float* __restrict__ bias,
                                              const float* __restrict__ rw,
                                              const float* __restrict__ rb,
                                              float* __restrict__ io, int N) {
  __shared__ float xs[16][68];
  const int g = threadIdx.x >> 4, li = threadIdx.x & 15;
  const int n = blockIdx.x * 16 + g;
  if (n >= N) return;
  *reinterpret_cast<float4*>(&xs[g][li * 4]) =
      *reinterpret_cast<const float4*>(h + (size_t)n * DIM + li * 4);
  float r0 = 0.f, r1 = 0.f, r2 = 0.f, r3 = 0.f;
  float s0 = 0.f, s1 = 0.f, s2 = 0.f, s3 = 0.f;
#pragma unroll 8
  for (int k = 0; k < DIM; ++k) {
    const float hd = xs[g][k];
    const float4 w = *reinterpret_cast<const float4*>(root + k * DIM + li * 4);
    const float4 v = *reinterpret_cast<const float4*>(rw + k * DIM + li * 4);
    r0 += hd * w.x; r1 += hd * w.y; r2 += hd * w.z; r3 += hd * w.w;
    s0 += hd * v.x; s1 += hd * v.y; s2 += hd * v.z; s3 += hd * v.w;
  }
  float* o = io + (size_t)n * DIM + li * 4;
  const float4 acc = *reinterpret_cast<const float4*>(o);
  const float4 b = *reinterpret_cast<const float4*>(bias + li * 4);
  const float4 c = *reinterpret_cast<const float4*>(rb + li * 4);
  float o0 = fmaxf(acc.x + r0 + b.x, 0.f) + fmaxf(s0 + c.x, 0.f);
  float o1 = fmaxf(acc.y + r1 + b.y, 0.f) + fmaxf(s1 + c.y, 0.f);
  float o2 = fmaxf(acc.z + r2 + b.z, 0.f) + fmaxf(s2 + c.z, 0.f);
  float o3 = fmaxf(acc.w + r3 + b.w, 0.f) + fmaxf(s3 + c.w, 0.f);
  *reinterpret_cast<float4*>(o) = make_float4(o0, o1, o2, o3);
}

// ---------------- host ----------------

extern "C" void kernel_launch(void* const* d_in, const int* in_sizes, int n_in,
                              void* d_out, int out_size, void* d_ws, size_t ws_size,
                              hipStream_t stream) {
  const float* x    = (const float*)d_in[0];
  const int*   ei   = (const int*)d_in[1];
  const int*   et   = (const int*)d_in[2];
  const float* W    = (const float*)d_in[3];
  const float* root = (const float*)d_in[4];
  const float* bias = (const float*)d_in[5];
  const float* resW = (const float*)d_in[6];
  const float* resb = (const float*)d_in[7];
  float* out = (float*)d_out;

  const int* src = ei;
  const int* dstp = ei + EE;

  char* ws = (char*)d_ws;
  size_t off = 0;
  auto take = [&](size_t bytes) -> void* {
    void* p = ws + off;
    off = (off + bytes + 255) & ~(size_t)255;
    return p;
  };
  unsigned short* m = (unsigned short*)take((size_t)EE * DIM * sizeof(unsigned short));
  int* deg       = (int*)take((size_t)NN * sizeof(int));
  int* rowptr    = (int*)take((size_t)(NN + 1) * sizeof(int));
  int* poscur    = (int*)take((size_t)NN * sizeof(int));
  int* bhist     = (int*)take((size_t)NSB * RR * sizeof(int));
  int* boffrel   = (int*)take((size_t)NSB * RR * sizeof(int));
  int* total     = (int*)take((size_t)RR * sizeof(int));
  int* tptrg     = (int*)take((size_t)RR * sizeof(int));
  int* bsum      = (int*)take((size_t)SCAN_NB * sizeof(int));
  int* osrc      = (int*)take((size_t)EE * sizeof(int));
  int* opos      = (int*)take((size_t)EE * sizeof(int));
  float* oscale  = (float*)take((size_t)EE * sizeof(float));
  int4* chunkArr = (int4*)take((size_t)MAXCHUNKS * sizeof(int4));
  int* nchunks   = (int*)take(256);
  unsigned short* rt16 = (unsigned short*)take((size_t)NN * DIM * sizeof(unsigned short));
  unsigned short* rs16 = (unsigned short*)take((size_t)NN * DIM * sizeof(unsigned short));
  unsigned short* hbf  = (unsigned short*)take((size_t)NN * DIM * sizeof(unsigned short));
  unsigned short* wbt  = (unsigned short*)take((size_t)2 * RR * DIM * DIM * sizeof(unsigned short));
  const size_t main_off = off;
  unsigned int* cnt32 = (unsigned int*)m;           // alias: uint16[R][N] = 6.5MB
  const unsigned short* c16 = (const unsigned short*)m;

  if (main_off <= ws_size) {
    // 1: fused setup (zero cnt | W->bf16^T | x->bf16)
    setup_k<<<ZB + CB + HB, 256, 0, stream>>>((int4*)cnt32, W, wbt, x, hbf);
    // 2: histograms
    hist_k<<<NSB, 512, 0, stream>>>(dstp, et, cnt32, bhist, EE);
    // 3: [deg reduce | per-relation prefix (2 items/thread)]
    scanA_k<<<SCAN_NB + RR, 1024, 0, stream>>>(c16, deg, bsum, bhist, boffrel, total);
    // 4: [bsum scan | type totals -> chunks]
    scanB_k<<<2, 128, 0, stream>>>(bsum, total, tptrg, chunkArr, nchunks);
    // 5: node rowptr
    scan3_k<<<SCAN_NB, 1024, 0, stream>>>(deg, bsum, rowptr, poscur);
    // 6: edge scatter
    scatter_k<<<NSB, 512, 0, stream>>>(src, dstp, et, c16, boffrel, tptrg, poscur,
                                       osrc, opos, oscale, EE);

    const int XG = (NN + XNB - 1) / XNB;
    // layer 0: x -> hbf(h1)
    xform_k<true><<<XG, 256, 0, stream>>>(x, root, bias, resW, resb, rt16, rs16, NN);
    msgm_k<<<MAXCHUNKS, 256, 0, stream>>>(hbf, osrc, opos, oscale, wbt, chunkArr, nchunks, m);
    gather2_k<true><<<(NN + 15) / 16, 256, 0, stream>>>(m, rowptr, rt16, rs16, hbf, NN);
    // layer 1: hbf(h1) -> out (f32)
    xform_k<false><<<XG, 256, 0, stream>>>(hbf, root + DIM * DIM, bias + DIM,
                                           resW + DIM * DIM, resb + DIM, rt16, rs16, NN);
    msgm_k<<<MAXCHUNKS, 256, 0, stream>>>(hbf, osrc, opos, oscale,
                                          wbt + (size_t)RR * DIM * DIM, chunkArr, nchunks, m);
    gather2_k<false><<<(NN + 15) / 16, 256, 0, stream>>>(m, rowptr, rt16, rs16, out, NN);
  } else {
    // ---- fallback: atomic path (needs only 25.8 MB) ----
    int* fcnt = (int*)ws;
    float* fh1 = (float*)(ws + (size_t)NN * RR * sizeof(int));
    hipMemsetAsync(fcnt, 0, (size_t)NN * RR * sizeof(int), stream);
    hipMemsetAsync(fh1, 0, (size_t)NN * DIM * sizeof(float), stream);
    hipMemsetAsync(out, 0, (size_t)NN * DIM * sizeof(float), stream);
    count_k<<<(EE + 255) / 256, 256, 0, stream>>>(dstp, et, fcnt, EE);
    edge_k<<<(EE + 15) / 16, 256, 0, stream>>>(x, src, dstp, et, W, fcnt, fh1, EE);
    node_k<<<(NN + 15) / 16, 256, 0, stream>>>(x, root, bias, resW, resb, fh1, NN);
    edge_k<<<(EE + 15) / 16, 256, 0, stream>>>(fh1, src, dstp, et,
                                               W + (size_t)RR * DIM * DIM, fcnt, out, EE);
    node_k<<<(NN + 15) / 16, 256, 0, stream>>>(fh1, root + DIM * DIM, bias + DIM,
                                               resW + DIM * DIM, resb + DIM, out, NN);
  }
}

// Round 16
// 224.185 us; speedup vs baseline: 1.2585x; 1.0009x over previous
//
#include <hip/hip_runtime.h>

// RGCN: N=50000, E=600000, D=64, R=65, L=2.
// out_i = relu( sum_r mean_{j in N_r(i)} x_j@W_r + x_i@root + b ) + relu( x_i@res_W + res_b )
// Counting-sort pipeline (relation-sort -> MFMA W reuse; dst-sort -> CSR gather).
// Round-16: verbatim revert to round-14 (best-known-good, 224.4us). Round-15's
// xform||msgm block-split fusion corrupted results (absmax 3.19) via the shared
// char[]/reinterpret LDS union; root cause unverified -> abandoned (upside ~5%).

constexpr int NN  = 50000;
constexpr int EE  = 600000;
constexpr int DIM = 64;
constexpr int RR  = 65;
constexpr int CHUNK = 256;                        // edges per msgm relation-chunk
constexpr int MAXCHUNKS = EE / CHUNK + RR + 8;
constexpr int SORT_BS = 512;                      // edges per sort block
constexpr int NSB = (EE + SORT_BS - 1) / SORT_BS; // 1172
constexpr int SCAN_BS = 1024;
constexpr int SCAN_NB = (NN + SCAN_BS - 1) / SCAN_BS; // 49
constexpr int XNB = 64;                           // nodes per xform block

typedef __attribute__((ext_vector_type(8))) short short8v;
typedef __attribute__((ext_vector_type(4))) float floatx4;

__device__ inline unsigned short f2bf(float f) {
  unsigned int u = __float_as_uint(f);
  return (unsigned short)((u + 0x7fffu + ((u >> 16) & 1u)) >> 16);  // RNE
}
__device__ inline float bf2f(unsigned short v) {
  return __uint_as_float(((unsigned int)v) << 16);
}

// ---------------- fused setup kernel: zero cnt | cvt W | cvt x ----------------

constexpr int ZN4 = NN * RR * 2 / 16;             // int4 count of uint16 cnt (6.5MB)
constexpr int ZB  = (ZN4 + 255) / 256;
constexpr int CW4 = 2 * RR * DIM * DIM / 4;       // float4 count of W
constexpr int CB  = (CW4 + 255) / 256;
constexpr int HB  = (NN * DIM / 8 + 255) / 256;

__global__ __launch_bounds__(256) void setup_k(int4* __restrict__ zp,
                                               const float* __restrict__ W,
                                               unsigned short* __restrict__ WT,
                                               const float* __restrict__ x,
                                               unsigned short* __restrict__ hbf) {
  const int b = blockIdx.x;
  if (b < ZB) {
    const int i = b * 256 + threadIdx.x;
    if (i < ZN4) zp[i] = make_int4(0, 0, 0, 0);
  } else if (b < ZB + CB) {
    // W[l][r][k][c] f32 -> WT[l*R+r][c][k] bf16 (transposed)
    const int tid = (b - ZB) * 256 + threadIdx.x;
    if (tid >= CW4) return;
    const int base = tid * 4;
    const int mat = base >> 12, rem = base & 4095;
    const int k = rem >> 6, c0 = rem & 63;
    const float4 v = *reinterpret_cast<const float4*>(W + base);
    unsigned short* o = WT + (size_t)mat * 4096;
    o[(c0 + 0) * 64 + k] = f2bf(v.x);
    o[(c0 + 1) * 64 + k] = f2bf(v.y);
    o[(c0 + 2) * 64 + k] = f2bf(v.z);
    o[(c0 + 3) * 64 + k] = f2bf(v.w);
  } else {
    const int tid = (b - ZB - CB) * 256 + threadIdx.x;   // 8 elems per thread
    if (tid * 8 >= NN * DIM) return;
    const float4 v0 = reinterpret_cast<const float4*>(x)[tid * 2];
    const float4 v1 = reinterpret_cast<const float4*>(x)[tid * 2 + 1];
    ushort4 a, c;
    a.x = f2bf(v0.x); a.y = f2bf(v0.y); a.z = f2bf(v0.z); a.w = f2bf(v0.w);
    c.x = f2bf(v1.x); c.y = f2bf(v1.y); c.z = f2bf(v1.z); c.w = f2bf(v1.w);
    reinterpret_cast<ushort4*>(hbf)[tid * 2] = a;
    reinterpret_cast<ushort4*>(hbf)[tid * 2 + 1] = c;
  }
}

// Fused: uint16 (d,r)-histogram via packed 32-bit atomics + per-block LDS type hist.
__global__ __launch_bounds__(512) void hist_k(const int* __restrict__ dst,
                                              const int* __restrict__ et,
                                              unsigned int* __restrict__ cnt32,
                                              int* __restrict__ bhist, int E) {
  __shared__ int lh[RR];
  if (threadIdx.x < RR) lh[threadIdx.x] = 0;
  __syncthreads();
  const int e = blockIdx.x * SORT_BS + threadIdx.x;
  if (e < E) {
    const int d = dst[e], r = et[e];
    const int c = r * NN + d;                        // [R][N] layout
    atomicAdd(&cnt32[c >> 1], 1u << (16 * (c & 1))); // 16-bit halfword bump
    atomicAdd(&lh[r], 1);                            // LDS
  }
  __syncthreads();
  if (threadIdx.x < RR) bhist[blockIdx.x * RR + threadIdx.x] = lh[threadIdx.x];
}

// ---- fused scanA: [deg-from-cnt block-reduce | per-relation block prefix] ----
// Per-relation prefix handles NSB=1172 via 2 items per thread.

__global__ __launch_bounds__(1024) void scanA_k(const unsigned short* __restrict__ c16,
                                                int* __restrict__ deg,
                                                int* __restrict__ bsum,
                                                const int* __restrict__ bhist,
                                                int* __restrict__ boffrel,
                                                int* __restrict__ total) {
  __shared__ int s[SCAN_BS];
  const int t = threadIdx.x;
  if (blockIdx.x < SCAN_NB) {
    const int idx = blockIdx.x * SCAN_BS + t;
    int d = 0;
    if (idx < NN) {
#pragma unroll 13
      for (int r = 0; r < RR; ++r) d += c16[r * NN + idx];  // coalesced 2B
      deg[idx] = d;
    }
    s[t] = d;
    __syncthreads();
    for (int off = SCAN_BS / 2; off > 0; off >>= 1) {
      if (t < off) s[t] += s[t + off];
      __syncthreads();
    }
    if (t == 0) bsum[blockIdx.x] = s[0];
  } else {
    const int r = blockIdx.x - SCAN_NB;        // relation
    const int i0 = 2 * t, i1 = 2 * t + 1;
    const int v0 = (i0 < NSB) ? bhist[i0 * RR + r] : 0;
    const int v1 = (i1 < NSB) ? bhist[i1 * RR + r] : 0;
    s[t] = v0 + v1;
    __syncthreads();
    for (int off = 1; off < SCAN_BS; off <<= 1) {   // inclusive over pair-sums
      const int u = (t >= off) ? s[t - off] : 0;
      __syncthreads();
      s[t] += u;
      __syncthreads();
    }
    const int excl = s[t] - v0 - v1;                // exclusive before item i0
    if (i0 < NSB) boffrel[i0 * RR + r] = excl;
    if (i1 < NSB) boffrel[i1 * RR + r] = excl + v0;
    if (t == SCAN_BS - 1) total[r] = s[SCAN_BS - 1];
  }
}

// ---- fused scanB: [wave-scan bsum | type totals -> tptr + chunks] ----

__global__ __launch_bounds__(128) void scanB_k(int* __restrict__ bsum,
                                               const int* __restrict__ total,
                                               int* __restrict__ tptrg,
                                               int4* __restrict__ chunkArr,
                                               int* __restrict__ nchunks) {
  const int t = threadIdx.x;
  if (blockIdx.x == 0) {
    if (t < 64) {
      int v = (t < SCAN_NB) ? bsum[t] : 0;
      const int orig = v;
      for (int off = 1; off < 64; off <<= 1) {
        const int u = __shfl_up(v, off, 64);
        if (t >= off) v += u;
      }
      if (t < SCAN_NB) bsum[t] = v - orig;   // exclusive
    }
  } else {
    __shared__ int tptr[RR + 1], chbase[RR + 1];
    if (t == 0) {
      int run = 0, crun = 0;
      for (int r = 0; r < RR; ++r) {
        tptr[r] = run;    run  += total[r];
        chbase[r] = crun; crun += (total[r] + CHUNK - 1) / CHUNK;
      }
      tptr[RR] = run; chbase[RR] = crun;
      *nchunks = crun;
    }
    __syncthreads();
    if (t < RR) {
      tptrg[t] = tptr[t];
      const int tot = total[t];
      const int nc = (tot + CHUNK - 1) / CHUNK;
      for (int i = 0; i < nc; ++i) {
        const int beg = tptr[t] + i * CHUNK;
        chunkArr[chbase[t] + i] = make_int4(beg, min(beg + CHUNK, tptr[t] + tot), t, 0);
      }
    }
  }
}

__global__ __launch_bounds__(1024) void scan3_k(const int* __restrict__ deg,
                                                const int* __restrict__ bsum,
                                                int* __restrict__ rowptr,
                                                int* __restrict__ poscur) {
  __shared__ int s[SCAN_BS];
  const int t = threadIdx.x;
  const int idx = blockIdx.x * SCAN_BS + t;
  const int v = (idx < NN) ? deg[idx] : 0;
  s[t] = v;
  __syncthreads();
  for (int off = 1; off < SCAN_BS; off <<= 1) {  // Hillis-Steele inclusive
    const int u = (t >= off) ? s[t - off] : 0;
    __syncthreads();
    s[t] += u;
    __syncthreads();
  }
  const int excl = bsum[blockIdx.x] + s[t] - v;
  if (idx < NN) { rowptr[idx] = excl; poscur[idx] = excl; }
  if (idx == NN - 1) rowptr[NN] = EE;
}

__global__ __launch_bounds__(512) void scatter_k(const int* __restrict__ src,
                                                 const int* __restrict__ dst,
                                                 const int* __restrict__ et,
                                                 const unsigned short* __restrict__ c16,
                                                 const int* __restrict__ boffrel,
                                                 const int* __restrict__ tptrg,
                                                 int* __restrict__ poscur,
                                                 int* __restrict__ osrc,
                                                 int* __restrict__ opos,
                                                 float* __restrict__ oscale, int E) {
  __shared__ int cur[RR];
  if (threadIdx.x < RR)
    cur[threadIdx.x] = tptrg[threadIdx.x] + boffrel[blockIdx.x * RR + threadIdx.x];
  __syncthreads();
  const int e = blockIdx.x * SORT_BS + threadIdx.x;
  if (e < E) {
    const int s = src[e], d = dst[e], r = et[e];
    const int q = atomicAdd(&cur[r], 1);       // LDS atomic, block-local
    const int p = atomicAdd(&poscur[d], 1);    // global, ~12 avg contention
    osrc[q] = s;
    opos[q] = p;
    oscale[q] = 1.0f / (float)c16[r * NN + d]; // 2B random read, L2-resident
  }
}

// ---------------- per-layer kernels ----------------

// MFMA message kernel: one block per 256-edge relation-chunk, 4 waves x 64 edges.
__global__ __launch_bounds__(256) void msgm_k(const unsigned short* __restrict__ hbf,
                                              const int* __restrict__ osrc,
                                              const int* __restrict__ opos,
                                              const float* __restrict__ oscale,
                                              const unsigned short* __restrict__ WT,
                                              const int4* __restrict__ chunkArr,
                                              const int* __restrict__ nchunks,
                                              unsigned short* __restrict__ m) {
  const int ci = blockIdx.x;
  if (ci >= *nchunks) return;
  const int4 c = chunkArr[ci];
  const int beg = c.x, end = c.y, rel = c.z;

  __shared__ unsigned short Wl[DIM][72];   // +8 pad
  {
    const float4* s4 = reinterpret_cast<const float4*>(WT + (size_t)rel * 4096);
#pragma unroll
    for (int it = 0; it < 2; ++it) {
      const int seg = threadIdx.x + it * 256;   // 512 x 16B segments
      const int row = seg >> 3, s8 = seg & 7;
      *reinterpret_cast<float4*>(&Wl[row][s8 * 8]) = s4[seg];
    }
  }
  __syncthreads();

  const int w  = threadIdx.x >> 6;
  const int l  = threadIdx.x & 63;
  const int lr = l & 15, lq = l >> 4;

  const int ebase = beg + w * 64;
  if (ebase >= end) return;                // no barriers after this point

  short8v a[4][2];
#pragma unroll
  for (int ct = 0; ct < 4; ++ct)
#pragma unroll
    for (int kk = 0; kk < 2; ++kk)
      a[ct][kk] = *reinterpret_cast<const short8v*>(&Wl[ct * 16 + lr][kk * 32 + lq * 8]);

  short8v b[4][2];
  int eidx[4];
#pragma unroll
  for (int et = 0; et < 4; ++et) {
    eidx[et] = ebase + et * 16 + lr;
    const int e = min(eidx[et], end - 1);  // clamp (safe dup, store guarded)
    const int s = osrc[e];
    const unsigned short* hp = hbf + (size_t)s * DIM;
    b[et][0] = *reinterpret_cast<const short8v*>(hp + lq * 8);
    b[et][1] = *reinterpret_cast<const short8v*>(hp + 32 + lq * 8);
  }

  floatx4 acc[4][4];
#pragma unroll
  for (int ct = 0; ct < 4; ++ct)
#pragma unroll
    for (int et = 0; et < 4; ++et)
      acc[ct][et] = (floatx4){0.f, 0.f, 0.f, 0.f};

#pragma unroll
  for (int kk = 0; kk < 2; ++kk)
#pragma unroll
    for (int ct = 0; ct < 4; ++ct)
#pragma unroll
      for (int et = 0; et < 4; ++et)
        acc[ct][et] = __builtin_amdgcn_mfma_f32_16x16x32_bf16(a[ct][kk], b[et][kk],
                                                              acc[ct][et], 0, 0, 0);

#pragma unroll
  for (int et = 0; et < 4; ++et) {
    const int e = eidx[et];
    if (e < end) {
      const float sc = oscale[e];
      unsigned short* op = m + (size_t)opos[e] * DIM;
#pragma unroll
      for (int ct = 0; ct < 4; ++ct) {
        ushort4 o;
        o.x = f2bf(acc[ct][et][0] * sc);
        o.y = f2bf(acc[ct][et][1] * sc);
        o.z = f2bf(acc[ct][et][2] * sc);
        o.w = f2bf(acc[ct][et][3] * sc);
        *reinterpret_cast<ushort4*>(op + ct * 16 + lq * 4) = o;
      }
    }
  }
}

// Dense node transform: rt16 = bf16(h@root + b), rs16 = bf16(relu(h@rw + rb)).
template<bool F32SRC>
__global__ __launch_bounds__(256) void xform_k(const void* __restrict__ hsrc,
                                               const float* __restrict__ root,
                                               const float* __restrict__ bias,
                                               const float* __restrict__ rw,
                                               const float* __restrict__ rb,
                                               unsigned short* __restrict__ rt16,
                                               unsigned short* __restrict__ rs16, int N) {
  __shared__ float Wl0[DIM * DIM];
  __shared__ float Wl1[DIM * DIM];
  __shared__ float xs[XNB][68];
#pragma unroll
  for (int i = 0; i < 4; ++i) {
    reinterpret_cast<float4*>(Wl0)[threadIdx.x + i * 256] =
        reinterpret_cast<const float4*>(root)[threadIdx.x + i * 256];
    reinterpret_cast<float4*>(Wl1)[threadIdx.x + i * 256] =
        reinterpret_cast<const float4*>(rw)[threadIdx.x + i * 256];
  }

  const int g = threadIdx.x >> 4, li = threadIdx.x & 15;
  const int base = blockIdx.x * XNB;
#pragma unroll
  for (int r = 0; r < 4; ++r) {
    const int n = base + g * 4 + r;
    float4 v = make_float4(0.f, 0.f, 0.f, 0.f);
    if (n < N) {
      if (F32SRC) {
        v = *reinterpret_cast<const float4*>((const float*)hsrc + (size_t)n * DIM + li * 4);
      } else {
        const ushort4 u = *reinterpret_cast<const ushort4*>(
            (const unsigned short*)hsrc + (size_t)n * DIM + li * 4);
        v = make_float4(bf2f(u.x), bf2f(u.y), bf2f(u.z), bf2f(u.w));
      }
    }
    *reinterpret_cast<float4*>(&xs[g * 4 + r][li * 4]) = v;
  }
  __syncthreads();

  float aR[4][4], aS[4][4];
#pragma unroll
  for (int r = 0; r < 4; ++r)
#pragma unroll
    for (int q = 0; q < 4; ++q) { aR[r][q] = 0.f; aS[r][q] = 0.f; }

#pragma unroll 4
  for (int k = 0; k < DIM; ++k) {
    const float4 wr = *reinterpret_cast<const float4*>(&Wl0[k * DIM + li * 4]);
    const float4 wv = *reinterpret_cast<const float4*>(&Wl1[k * DIM + li * 4]);
#pragma unroll
    for (int r = 0; r < 4; ++r) {
      const float xv = xs[g * 4 + r][k];
      aR[r][0] += xv * wr.x; aR[r][1] += xv * wr.y; aR[r][2] += xv * wr.z; aR[r][3] += xv * wr.w;
      aS[r][0] += xv * wv.x; aS[r][1] += xv * wv.y; aS[r][2] += xv * wv.z; aS[r][3] += xv * wv.w;
    }
  }

  const float4 bv = reinterpret_cast<const float4*>(bias)[li];
  const float4 cv = reinterpret_cast<const float4*>(rb)[li];
#pragma unroll
  for (int r = 0; r < 4; ++r) {
    const int n = base + g * 4 + r;
    if (n < N) {
      ushort4 t, s;
      t.x = f2bf(aR[r][0] + bv.x); t.y = f2bf(aR[r][1] + bv.y);
      t.z = f2bf(aR[r][2] + bv.z); t.w = f2bf(aR[r][3] + bv.w);
      s.x = f2bf(fmaxf(aS[r][0] + cv.x, 0.f)); s.y = f2bf(fmaxf(aS[r][1] + cv.y, 0.f));
      s.z = f2bf(fmaxf(aS[r][2] + cv.z, 0.f)); s.w = f2bf(fmaxf(aS[r][3] + cv.w, 0.f));
      *reinterpret_cast<ushort4*>(rt16 + (size_t)n * DIM + li * 4) = t;
      *reinterpret_cast<ushort4*>(rs16 + (size_t)n * DIM + li * 4) = s;
    }
  }
}

// Streaming epilogue: out = relu(sum(msgs) + rt) + rs. Output bf16 (next h) or f32.
template<bool OUT_BF16>
__global__ __launch_bounds__(256) void gather2_k(const unsigned short* __restrict__ m,
                                                 const int* __restrict__ rowptr,
                                                 const unsigned short* __restrict__ rt16,
                                                 const unsigned short* __restrict__ rs16,
                                                 void* __restrict__ hout, int N) {
  const int g = threadIdx.x >> 4, li = threadIdx.x & 15;
  const int n = blockIdx.x * 16 + g;
  if (n >= N) return;

  float a0 = 0.f, a1 = 0.f, a2 = 0.f, a3 = 0.f;
  const int jb = rowptr[n], je = rowptr[n + 1];
  int j = jb;
  for (; j + 8 <= je; j += 8) {            // 8 independent loads in flight
    ushort4 v[8];
#pragma unroll
    for (int u = 0; u < 8; ++u)
      v[u] = *reinterpret_cast<const ushort4*>(m + (size_t)(j + u) * DIM + li * 4);
#pragma unroll
    for (int u = 0; u < 8; ++u) {
      a0 += bf2f(v[u].x); a1 += bf2f(v[u].y); a2 += bf2f(v[u].z); a3 += bf2f(v[u].w);
    }
  }
  for (; j + 4 <= je; j += 4) {
    ushort4 v[4];
#pragma unroll
    for (int u = 0; u < 4; ++u)
      v[u] = *reinterpret_cast<const ushort4*>(m + (size_t)(j + u) * DIM + li * 4);
#pragma unroll
    for (int u = 0; u < 4; ++u) {
      a0 += bf2f(v[u].x); a1 += bf2f(v[u].y); a2 += bf2f(v[u].z); a3 += bf2f(v[u].w);
    }
  }
  for (; j < je; ++j) {
    const ushort4 v = *reinterpret_cast<const ushort4*>(m + (size_t)j * DIM + li * 4);
    a0 += bf2f(v.x); a1 += bf2f(v.y); a2 += bf2f(v.z); a3 += bf2f(v.w);
  }

  const ushort4 tu = *reinterpret_cast<const ushort4*>(rt16 + (size_t)n * DIM + li * 4);
  const ushort4 su = *reinterpret_cast<const ushort4*>(rs16 + (size_t)n * DIM + li * 4);
  const float o0 = fmaxf(a0 + bf2f(tu.x), 0.f) + bf2f(su.x);
  const float o1 = fmaxf(a1 + bf2f(tu.y), 0.f) + bf2f(su.y);
  const float o2 = fmaxf(a2 + bf2f(tu.z), 0.f) + bf2f(su.z);
  const float o3 = fmaxf(a3 + bf2f(tu.w), 0.f) + bf2f(su.w);
  if (OUT_BF16) {
    ushort4 o;
    o.x = f2bf(o0); o.y = f2bf(o1); o.z = f2bf(o2); o.w = f2bf(o3);
    *reinterpret_cast<ushort4*>((unsigned short*)hout + (size_t)n * DIM + li * 4) = o;
  } else {
    *reinterpret_cast<float4*>((float*)hout + (size_t)n * DIM + li * 4) =
        make_float4(o0, o1, o2, o3);
  }
}

// ---------------- last-resort fallback (float atomics, self-contained) ----------------

__global__ __launch_bounds__(256) void count_k(const int* __restrict__ dst,
                                               const int* __restrict__ et,
                                               int* __restrict__ cnt, int E) {
  int e = blockIdx.x * 256 + threadIdx.x;
  if (e < E) atomicAdd(&cnt[dst[e] * RR + et[e]], 1);
}

__global__ __launch_bounds__(256) void edge_k(const float* __restrict__ h,
                                              const int* __restrict__ src,
                                              const int* __restrict__ dst,
                                              const int* __restrict__ et,
                                              const float* __restrict__ W,
                                              const int* __restrict__ cnt,
                                              float* __restrict__ accum, int E) {
  __shared__ float xs[16][68];
  const int g = threadIdx.x >> 4, li = threadIdx.x & 15;
  const int e = blockIdx.x * 16 + g;
  if (e >= E) return;
  const int s = src[e], d = dst[e], t = et[e];
  *reinterpret_cast<float4*>(&xs[g][li * 4]) =
      *reinterpret_cast<const float4*>(h + (size_t)s * DIM + li * 4);
  const float* Wt = W + (size_t)t * (DIM * DIM) + li * 4;
  float a0 = 0.f, a1 = 0.f, a2 = 0.f, a3 = 0.f;
#pragma unroll 8
  for (int k = 0; k < DIM; ++k) {
    const float xd = xs[g][k];
    const float4 w = *reinterpret_cast<const float4*>(Wt + k * DIM);
    a0 += xd * w.x; a1 += xd * w.y; a2 += xd * w.z; a3 += xd * w.w;
  }
  const float sc = 1.0f / (float)cnt[d * RR + t];
  float* o = accum + (size_t)d * DIM + li * 4;
  unsafeAtomicAdd(o + 0, a0 * sc);
  unsafeAtomicAdd(o + 1, a1 * sc);
  unsafeAtomicAdd(o + 2, a2 * sc);
  unsafeAtomicAdd(o + 3, a3 * sc);
}

__global__ __launch_bounds__(256) void node_k(const float* __restrict__ h,
                                              const float* __restrict__ root,
                                              const float* __restrict__ bias,
                                              const float* __restrict__ rw,
                                              const float* __restrict__ rb,
                                              float* __restrict__ io, int N) {
  __shared__ float xs[16][68];
  const int g = threadIdx.x >> 4, li = threadIdx.x & 15;
  const int n = blockIdx.x * 16 + g;
  if (n >= N) return;
  *reinterpret_cast<float4*>(&xs[g][li * 4]) =
      *reinterpret_cast<const float4*>(h + (size_t)n * DIM + li * 4);
  float r0 = 0.f, r1 = 0.f, r2 = 0.f, r3 = 0.f;
  float s0 = 0.f, s1 = 0.f, s2 = 0.f, s3 = 0.f;
#pragma unroll 8
  for (int k = 0; k < DIM; ++k) {
    const float hd = xs[g][k];
    const float4 w = *reinterpret_cast<const float4*>(root + k * DIM + li * 4);
    const float4 v = *reinterpret_cast<const float4*>(rw + k * DIM + li * 4);
    r0 += hd * w.x; r1 += hd * w.y; r2 += hd * w.z; r3 += hd * w.w;
    s0 += hd * v.x; s1 += hd * v.y; s2 += hd * v.z; s3 += hd * v.w;
  }
  float* o = io + (size_t)n * DIM + li * 4;
  const float4 acc = *reinterpret_cast<const float4*>(o);
  const float4 b = *reinterpret_cast<const float4*>(bias + li * 4);
  const float4 c = *reinterpret_cast<const float4*>(rb + li * 4);
  float o0 = fmaxf(acc.x + r0 + b.x, 0.f) + fmaxf(s0 + c.x, 0.f);
  float o1 = fmaxf(acc.y + r1 + b.y, 0.f) + fmaxf(s1 + c.y, 0.f);
  float o2 = fmaxf(acc.z + r2 + b.z, 0.f) + fmaxf(s2 + c.z, 0.f);
  float o3 = fmaxf(acc.w + r3 + b.w, 0.f) + fmaxf(s3 + c.w, 0.f);
  *reinterpret_cast<float4*>(o) = make_float4(o0, o1, o2, o3);
}

// ---------------- host ----------------

extern "C" void kernel_launch(void* const* d_in, const int* in_sizes, int n_in,
                              void* d_out, int out_size, void* d_ws, size_t ws_size,
                              hipStream_t stream) {
  const float* x    = (const float*)d_in[0];
  const int*   ei   = (const int*)d_in[1];
  const int*   et   = (const int*)d_in[2];
  const float* W    = (const float*)d_in[3];
  const float* root = (const float*)d_in[4];
  const float* bias = (const float*)d_in[5];
  const float* resW = (const float*)d_in[6];
  const float* resb = (const float*)d_in[7];
  float* out = (float*)d_out;

  const int* src = ei;
  const int* dstp = ei + EE;

  char* ws = (char*)d_ws;
  size_t off = 0;
  auto take = [&](size_t bytes) -> void* {
    void* p = ws + off;
    off = (off + bytes + 255) & ~(size_t)255;
    return p;
  };
  unsigned short* m = (unsigned short*)take((size_t)EE * DIM * sizeof(unsigned short));
  int* deg       = (int*)take((size_t)NN * sizeof(int));
  int* rowptr    = (int*)take((size_t)(NN + 1) * sizeof(int));
  int* poscur    = (int*)take((size_t)NN * sizeof(int));
  int* bhist     = (int*)take((size_t)NSB * RR * sizeof(int));
  int* boffrel   = (int*)take((size_t)NSB * RR * sizeof(int));
  int* total     = (int*)take((size_t)RR * sizeof(int));
  int* tptrg     = (int*)take((size_t)RR * sizeof(int));
  int* bsum      = (int*)take((size_t)SCAN_NB * sizeof(int));
  int* osrc      = (int*)take((size_t)EE * sizeof(int));
  int* opos      = (int*)take((size_t)EE * sizeof(int));
  float* oscale  = (float*)take((size_t)EE * sizeof(float));
  int4* chunkArr = (int4*)take((size_t)MAXCHUNKS * sizeof(int4));
  int* nchunks   = (int*)take(256);
  unsigned short* rt16 = (unsigned short*)take((size_t)NN * DIM * sizeof(unsigned short));
  unsigned short* rs16 = (unsigned short*)take((size_t)NN * DIM * sizeof(unsigned short));
  unsigned short* hbf  = (unsigned short*)take((size_t)NN * DIM * sizeof(unsigned short));
  unsigned short* wbt  = (unsigned short*)take((size_t)2 * RR * DIM * DIM * sizeof(unsigned short));
  const size_t main_off = off;
  unsigned int* cnt32 = (unsigned int*)m;           // alias: uint16[R][N] = 6.5MB
  const unsigned short* c16 = (const unsigned short*)m;

  if (main_off <= ws_size) {
    // 1: fused setup (zero cnt | W->bf16^T | x->bf16)
    setup_k<<<ZB + CB + HB, 256, 0, stream>>>((int4*)cnt32, W, wbt, x, hbf);
    // 2: histograms
    hist_k<<<NSB, 512, 0, stream>>>(dstp, et, cnt32, bhist, EE);
    // 3: [deg reduce | per-relation prefix (2 items/thread)]
    scanA_k<<<SCAN_NB + RR, 1024, 0, stream>>>(c16, deg, bsum, bhist, boffrel, total);
    // 4: [bsum scan | type totals -> chunks]
    scanB_k<<<2, 128, 0, stream>>>(bsum, total, tptrg, chunkArr, nchunks);
    // 5: node rowptr
    scan3_k<<<SCAN_NB, 1024, 0, stream>>>(deg, bsum, rowptr, poscur);
    // 6: edge scatter
    scatter_k<<<NSB, 512, 0, stream>>>(src, dstp, et, c16, boffrel, tptrg, poscur,
                                       osrc, opos, oscale, EE);

    const int XG = (NN + XNB - 1) / XNB;
    // layer 0: x -> hbf(h1)
    xform_k<true><<<XG, 256, 0, stream>>>(x, root, bias, resW, resb, rt16, rs16, NN);
    msgm_k<<<MAXCHUNKS, 256, 0, stream>>>(hbf, osrc, opos, oscale, wbt, chunkArr, nchunks, m);
    gather2_k<true><<<(NN + 15) / 16, 256, 0, stream>>>(m, rowptr, rt16, rs16, hbf, NN);
    // layer 1: hbf(h1) -> out (f32)
    xform_k<false><<<XG, 256, 0, stream>>>(hbf, root + DIM * DIM, bias + DIM,
                                           resW + DIM * DIM, resb + DIM, rt16, rs16, NN);
    msgm_k<<<MAXCHUNKS, 256, 0, stream>>>(hbf, osrc, opos, oscale,
                                          wbt + (size_t)RR * DIM * DIM, chunkArr, nchunks, m);
    gather2_k<false><<<(NN + 15) / 16, 256, 0, stream>>>(m, rowptr, rt16, rs16, out, NN);
  } else {
    // ---- fallback: atomic path (needs only 25.8 MB) ----
    int* fcnt = (int*)ws;
    float* fh1 = (float*)(ws + (size_t)NN * RR * sizeof(int));
    hipMemsetAsync(fcnt, 0, (size_t)NN * RR * sizeof(int), stream);
    hipMemsetAsync(fh1, 0, (size_t)NN * DIM * sizeof(float), stream);
    hipMemsetAsync(out, 0, (size_t)NN * DIM * sizeof(float), stream);
    count_k<<<(EE + 255) / 256, 256, 0, stream>>>(dstp, et, fcnt, EE);
    edge_k<<<(EE + 15) / 16, 256, 0, stream>>>(x, src, dstp, et, W, fcnt, fh1, EE);
    node_k<<<(NN + 15) / 16, 256, 0, stream>>>(x, root, bias, resW, resb, fh1, NN);
    edge_k<<<(EE + 15) / 16, 256, 0, stream>>>(fh1, src, dstp, et,
                                               W + (size_t)RR * DIM * DIM, fcnt, out, EE);
    node_k<<<(NN + 15) / 16, 256, 0, stream>>>(fh1, root + DIM * DIM, bias + DIM,
                                               resW + DIM * DIM, resb + DIM, out, NN);
  }
}